// Round 2
// baseline (788.196 us; speedup 1.0000x reference)
//
#include <hip/hip_runtime.h>
#include <cstdint>
#include <cstddef>

#define D 128
#define H 8
#define NSRC 200000
#define NE0  100000
#define NE1  50000
#define E0N  1000000
#define E1N  500000
#define NT   (NE0 + NE1)
#define ET   (E0N + E1N)

typedef unsigned short u16;
typedef __attribute__((ext_vector_type(8))) short short8;
typedef __attribute__((ext_vector_type(4))) float f32x4;
typedef __attribute__((ext_vector_type(2))) float f32x2;

// ---------- bf16 helpers ----------
__device__ __forceinline__ u16 f2bf(float f) {
  unsigned u = __float_as_uint(f);
  unsigned r = (u + 0x7fffu + ((u >> 16) & 1u)) >> 16;  // RNE
  return (u16)r;
}
__device__ __forceinline__ float bf2f(u16 u) {
  return __uint_as_float(((unsigned)u) << 16);
}
// unpack 2 packed bf16 (low = even dim) -> f32x2
__device__ __forceinline__ f32x2 unpk(unsigned u) {
  f32x2 r;
  r.x = __uint_as_float(u << 16);
  r.y = __uint_as_float(u & 0xffff0000u);
  return r;
}
// bf16 pair dot with f32 accumulate: d = a.lo*b.lo + a.hi*b.hi + c
__device__ __forceinline__ float dot2bf(unsigned a, unsigned b, float c) {
  float d;
  asm("v_dot2_f32_bf16 %0, %1, %2, %3" : "=v"(d) : "v"(a), "v"(b), "v"(c));
  return d;
}
__device__ __forceinline__ f32x2 fma2(f32x2 a, f32x2 b, f32x2 c) {
  return __builtin_elementwise_fma(a, b, c);
}

// ---------- mega-prep: x cast + weight transpose + emb GEMMs + zero-fill ----------
// block roles: [0,BC) cast | [BC,BC+64) weights | +4 embs | +BZ zero offs | +1 zero bn
#define BC 25000            // (NSRC*D/4)/256
#define BZ 147              // ceil((NT+1)/1024)
static_assert((size_t)BZ * 1024 >= NT + 1, "offs zero-fill must cover NT+1 entries");
__global__ __launch_bounds__(256) void prep_all(
    const float* __restrict__ x, u16* __restrict__ xb,
    const float* w0, const float* w1, const float* w2, const float* w3,
    const float* w4, const float* w5, const float* w6, const float* w7,
    u16* __restrict__ wt,
    const float* __restrict__ embA, const float* __restrict__ embB,
    const float* __restrict__ We0, const float* __restrict__ We1,
    float* __restrict__ kv,
    int* __restrict__ offs, float* __restrict__ bnsums) {
  int b = blockIdx.x;
  if (b < BC) {
    int i = b * 256 + threadIdx.x;
    float4 a = ((const float4*)x)[i];
    ushort4 o;
    o.x = f2bf(a.x); o.y = f2bf(a.y); o.z = f2bf(a.z); o.w = f2bf(a.w);
    ((ushort4*)xb)[i] = o;
  } else if (b < BC + 64) {
    int bb = b - BC;
    const float* wsrc[8] = {w0, w1, w2, w3, w4, w5, w6, w7};
    int mat = bb >> 3;
    int blk = bb & 7;
    const float* W = wsrc[mat];
    // fold 1/sqrt(d)=0.25 into Wq (mats 2 and 6) so Q comes out pre-scaled
    float sc = ((mat & 3) == 2) ? 0.25f : 1.0f;
    u16* out = wt + mat * 16384;
    for (int i = blk * 2048 + threadIdx.x; i < (blk + 1) * 2048; i += 256) {
      int n = i >> 7, k = i & 127;
      out[i] = f2bf(W[k * 128 + n] * sc);
    }
  } else if (b < BC + 68) {
    int bb = b - BC - 64;
    int mat = bb >> 1;
    int t = (bb & 1) * 256 + threadIdx.x;
    const float* We = mat ? We1 : We0;
    float* keOut = kv + mat * 1024;
    float* veOut = keOut + 512;
    int r = t >> 7, c = t & 127;
    float s0 = 0.f, s1 = 0.f;
    for (int k = 0; k < 128; ++k) {
      float w = We[k * 128 + c];
      s0 += embA[r * 128 + k] * w;
      s1 += embB[r * 128 + k] * w;
    }
    keOut[t] = s0;
    veOut[t] = s1;
  } else if (b < BC + 68 + BZ) {
    int base = (b - BC - 68) * 1024 + threadIdx.x * 4;
#pragma unroll
    for (int i = 0; i < 4; ++i)
      if (base + i < NT + 1) offs[base + i] = 0;
  } else {
    bnsums[threadIdx.x] = 0.f;  // 256 floats = bnsum|bnsq
  }
}

// ---------- quad-output MFMA GEMM (operand-swapped / transposed accumulators) ----
// mfma(b, a, acc): each lane owns ONE data row (lane&15 within rowset) and 4
// CONSECUTIVE output features per acc reg-quad -> 8B packed stores, 4x fewer
// store instructions, full 128B-line coverage (no partial-sector write amp).
// One dispatch does K/V (rows NA, interleaved into CKV as [K(8)|V(8)] per
// 8-dim group) + Q/S (rows NB, plain layout).
__global__ __launch_bounds__(256) void gemm_quad(
    const u16* __restrict__ A,
    const u16* __restrict__ WtK, const u16* __restrict__ WtV,
    u16* __restrict__ CKV, int NA, int nKV,
    const u16* __restrict__ WtQ, const u16* __restrict__ WtS,
    u16* __restrict__ CQ, u16* __restrict__ CS, int NB) {
  int b = blockIdx.x;
  const u16 *Wt0, *Wt1;
  int N, row0;
  bool ilv = (b < nKV);
  if (ilv) {
    Wt0 = WtK; Wt1 = WtV; N = NA; row0 = b * 128;
  } else {
    Wt0 = WtQ; Wt1 = WtS; N = NB; row0 = (b - nKV) * 128;
  }
  int w = threadIdx.x >> 6, lane = threadIdx.x & 63;
  int lrow = lane & 15, q = lane >> 4;
  row0 += w * 32;
  int ra = row0 + lrow;
  int rb = row0 + 16 + lrow;
  f32x4 acc[2][2][8];
#pragma unroll
  for (int o = 0; o < 2; ++o)
#pragma unroll
    for (int i = 0; i < 2; ++i)
#pragma unroll
      for (int j = 0; j < 8; ++j) acc[o][i][j] = (f32x4){0.f, 0.f, 0.f, 0.f};

  const short8 zero8 = {0, 0, 0, 0, 0, 0, 0, 0};
#pragma unroll
  for (int kk = 0; kk < 128; kk += 32) {
    int ko = kk + q * 8;
    short8 a0 = (ra < N) ? *(const short8*)(A + (size_t)ra * 128 + ko) : zero8;
    short8 a1 = (rb < N) ? *(const short8*)(A + (size_t)rb * 128 + ko) : zero8;
#pragma unroll
    for (int j = 0; j < 8; ++j) {
      short8 b0 = *(const short8*)(Wt0 + (j * 16 + lrow) * 128 + ko);
      short8 b1 = *(const short8*)(Wt1 + (j * 16 + lrow) * 128 + ko);
      // swapped operands: D^T mapping (lane&15 = data row, regs = 4 features)
      acc[0][0][j] = __builtin_amdgcn_mfma_f32_16x16x32_bf16(b0, a0, acc[0][0][j], 0, 0, 0);
      acc[0][1][j] = __builtin_amdgcn_mfma_f32_16x16x32_bf16(b0, a1, acc[0][1][j], 0, 0, 0);
      acc[1][0][j] = __builtin_amdgcn_mfma_f32_16x16x32_bf16(b1, a0, acc[1][0][j], 0, 0, 0);
      acc[1][1][j] = __builtin_amdgcn_mfma_f32_16x16x32_bf16(b1, a1, acc[1][1][j], 0, 0, 0);
    }
  }
  // epilogue: lane owns row (row0 + i*16 + lrow); features f = j*16 + q*4 + r
  if (ilv) {
#pragma unroll
    for (int i = 0; i < 2; ++i) {
      int grow = row0 + i * 16 + lrow;
      if (grow < N) {
#pragma unroll
        for (int o = 0; o < 2; ++o) {
          // f>>3 = 2j + (q>>1); f&7 = (q&1)*4 + r
          u16* base = CKV + (size_t)grow * 256 + (o << 3) + ((q & 1) << 2) + ((q >> 1) << 4);
#pragma unroll
          for (int j = 0; j < 8; ++j) {
            f32x4 v = acc[o][i][j];
            ushort4 pk;
            pk.x = f2bf(v[0]); pk.y = f2bf(v[1]); pk.z = f2bf(v[2]); pk.w = f2bf(v[3]);
            *(ushort4*)(base + j * 32) = pk;
          }
        }
      }
    }
  } else {
#pragma unroll
    for (int o = 0; o < 2; ++o) {
      u16* C = o ? CS : CQ;
#pragma unroll
      for (int i = 0; i < 2; ++i) {
        int grow = row0 + i * 16 + lrow;
        if (grow < N) {
          u16* base = C + (size_t)grow * 128 + q * 4;
#pragma unroll
          for (int j = 0; j < 8; ++j) {
            f32x4 v = acc[o][i][j];
            ushort4 pk;
            pk.x = f2bf(v[0]); pk.y = f2bf(v[1]); pk.z = f2bf(v[2]); pk.w = f2bf(v[3]);
            *(ushort4*)(base + j * 16) = pk;
          }
        }
      }
    }
  }
}

// ---------- CSR build (both layers, rank-based fill) ----------
__global__ __launch_bounds__(256) void csr_count2(
    const int* __restrict__ dst0, const int* __restrict__ dst1,
    int* __restrict__ cnt, int* __restrict__ rank) {
  int t = blockIdx.x * 256 + threadIdx.x;
  if (t < E0N) {
    rank[t] = atomicAdd(&cnt[dst0[t]], 1);
  } else if (t < ET) {
    rank[t] = atomicAdd(&cnt[NE0 + dst1[t - E0N]], 1);
  }
}

__global__ __launch_bounds__(256) void scan1(const int* __restrict__ cnt,
                                             int* __restrict__ excl,
                                             int* __restrict__ blocksums, int N) {
  __shared__ int sh[256];
  int tid = threadIdx.x;
  int base = blockIdx.x * 1024 + tid * 4;
  int v0 = (base + 0 < N) ? cnt[base + 0] : 0;
  int v1 = (base + 1 < N) ? cnt[base + 1] : 0;
  int v2 = (base + 2 < N) ? cnt[base + 2] : 0;
  int v3 = (base + 3 < N) ? cnt[base + 3] : 0;
  int tsum = v0 + v1 + v2 + v3;
  sh[tid] = tsum;
  __syncthreads();
  for (int off = 1; off < 256; off <<= 1) {
    int t2 = (tid >= off) ? sh[tid - off] : 0;
    __syncthreads();
    sh[tid] += t2;
    __syncthreads();
  }
  int incl = sh[tid];
  if (tid == 255) blocksums[blockIdx.x] = incl;
  int run = incl - tsum;
  if (base + 0 < N) excl[base + 0] = run; run += v0;
  if (base + 1 < N) excl[base + 1] = run; run += v1;
  if (base + 2 < N) excl[base + 2] = run; run += v2;
  if (base + 3 < N) excl[base + 3] = run;
}

__global__ void scan2(int* __restrict__ blocksums, int nb) {
  __shared__ int sh[256];
  int tid = threadIdx.x;
  int v = (tid < nb) ? blocksums[tid] : 0;
  sh[tid] = v;
  __syncthreads();
  for (int off = 1; off < 256; off <<= 1) {
    int t2 = (tid >= off) ? sh[tid - off] : 0;
    __syncthreads();
    sh[tid] += t2;
    __syncthreads();
  }
  if (tid < nb) blocksums[tid] = sh[tid] - v;
}

__global__ __launch_bounds__(256) void scan3(int* __restrict__ offs,
                                             const int* __restrict__ blocksums, int N,
                                             int Etot) {
  int t = blockIdx.x * 256 + threadIdx.x;
  if (t < N) offs[t] += blocksums[t >> 10];
  if (t == 0) offs[N] = Etot;
}

__global__ __launch_bounds__(256) void csr_fill2(
    const int* __restrict__ dst0, const int* __restrict__ src0, const int* __restrict__ et0,
    const int* __restrict__ dst1, const int* __restrict__ src1, const int* __restrict__ et1,
    const int* __restrict__ offs, const int* __restrict__ rank,
    int* __restrict__ elist) {
  int t = blockIdx.x * 256 + threadIdx.x;
  if (t < E0N) {
    int p = offs[dst0[t]] + rank[t];
    elist[p] = (src0[t] << 2) | et0[t];
  } else if (t < ET) {
    int t2 = t - E0N;
    int p = offs[NE0 + dst1[t2]] + rank[t];
    elist[p] = (src1[t2] << 2) | et1[t2];
  }
}

// ---------- fused flash attention + skip combine ----------
// 4 dsts/wave, 16 lanes/dst, 8 consecutive dims/lane.
// KV table is interleaved: row = 16 groups of {K[8] | V[8]} bf16.
// Q pre-scaled by 0.25 (folded into Wq).
__device__ __forceinline__ float sel4(float s0, float s1, float s2, float s3, int ty) {
  float a = (ty & 1) ? s1 : s0;
  float b = (ty & 1) ? s3 : s2;
  return (ty & 2) ? b : a;
}

__global__ __launch_bounds__(256) void attn_fused(
    const int* __restrict__ elist, const int* __restrict__ offs,
    const u16* __restrict__ Q, const u16* __restrict__ KV,
    const float* __restrict__ ke, const float* __restrict__ ve,
    const u16* __restrict__ skipb, float* __restrict__ outp, int N) {
  int wave = (blockIdx.x * 256 + threadIdx.x) >> 6;
  int lane = threadIdx.x & 63;
  int which = lane >> 4;   // dst slot within wave
  int sub = lane & 15;     // 16 lanes per dst
  int d = wave * 4 + which;
  bool active = d < N;
  int dc = active ? d : 0;
  int dim0 = sub * 8;      // 8 consecutive dims per lane; head = sub>>1
  int sub16 = sub * 16;    // u16 offset of this lane's group within a KV row

  // Q: 8 dims as 4 packed bf16 pairs (already scaled by 1/sqrt(d))
  uint4 qp = *(const uint4*)(Q + (size_t)dc * D + dim0);
  f32x2 u0 = unpk(qp.x), u1 = unpk(qp.y), u2 = unpk(qp.z), u3 = unpk(qp.w);

  // per-type q . (We ek) : reduce over head (2 lanes)
  float qk0, qk1, qk2, qk3;
#pragma unroll
  for (int ty = 0; ty < 4; ++ty) {
    const float* kt = ke + ty * D + dim0;
    float4 ka = *(const float4*)kt;
    float4 kb = *(const float4*)(kt + 4);
    float p = u0.x * ka.x + u0.y * ka.y + u1.x * ka.z + u1.y * ka.w +
              u2.x * kb.x + u2.y * kb.y + u3.x * kb.z + u3.y * kb.w;
    p += __shfl_xor(p, 1, 64);
    if (ty == 0) qk0 = p; else if (ty == 1) qk1 = p; else if (ty == 2) qk2 = p; else qk3 = p;
  }

  int j0 = active ? offs[d] : 0;
  int j1 = active ? offs[d + 1] : 0;
  int j = j0;

  // prefetched current batch: edge codes + K-part rows
  int cp0, cp1, cp2, cp3;
  uint4 ck0, ck1, ck2, ck3;
  {
    int i0 = (j + 0 < j1) ? j + 0 : 0;
    int i1 = (j + 1 < j1) ? j + 1 : 0;
    int i2 = (j + 2 < j1) ? j + 2 : 0;
    int i3 = (j + 3 < j1) ? j + 3 : 0;
    cp0 = elist[i0]; cp1 = elist[i1]; cp2 = elist[i2]; cp3 = elist[i3];
    ck0 = *(const uint4*)(KV + (size_t)(cp0 >> 2) * 256 + sub16);
    ck1 = *(const uint4*)(KV + (size_t)(cp1 >> 2) * 256 + sub16);
    ck2 = *(const uint4*)(KV + (size_t)(cp2 >> 2) * 256 + sub16);
    ck3 = *(const uint4*)(KV + (size_t)(cp3 >> 2) * 256 + sub16);
  }

  float m = -INFINITY, s = 0.f;
  f32x2 acc01 = {0.f, 0.f}, acc23 = {0.f, 0.f}, acc45 = {0.f, 0.f}, acc67 = {0.f, 0.f};

  while (__any(j < j1)) {
    int jn = j + 4;
    // prefetch next batch (K-part only; clamped)
    int i0 = (jn + 0 < j1) ? jn + 0 : 0;
    int i1 = (jn + 1 < j1) ? jn + 1 : 0;
    int i2 = (jn + 2 < j1) ? jn + 2 : 0;
    int i3 = (jn + 3 < j1) ? jn + 3 : 0;
    int np0 = elist[i0], np1 = elist[i1], np2 = elist[i2], np3 = elist[i3];
    uint4 nk0 = *(const uint4*)(KV + (size_t)(np0 >> 2) * 256 + sub16);
    uint4 nk1 = *(const uint4*)(KV + (size_t)(np1 >> 2) * 256 + sub16);
    uint4 nk2 = *(const uint4*)(KV + (size_t)(np2 >> 2) * 256 + sub16);
    uint4 nk3 = *(const uint4*)(KV + (size_t)(np3 >> 2) * 256 + sub16);

    int n = j1 - j;
    if (n > 0) {
      int t0 = cp0 & 3, t1 = cp1 & 3, t2 = cp2 & 3, t3 = cp3 & 3;
      // issue V-part + type-table loads early (addrs ready from prefetch)
      uint4 cv0 = *(const uint4*)(KV + (size_t)(cp0 >> 2) * 256 + sub16 + 8);
      uint4 cv1 = *(const uint4*)(KV + (size_t)(cp1 >> 2) * 256 + sub16 + 8);
      uint4 cv2 = *(const uint4*)(KV + (size_t)(cp2 >> 2) * 256 + sub16 + 8);
      uint4 cv3 = *(const uint4*)(KV + (size_t)(cp3 >> 2) * 256 + sub16 + 8);
      const float* vp0 = ve + t0 * D + dim0;
      const float* vp1 = ve + t1 * D + dim0;
      const float* vp2 = ve + t2 * D + dim0;
      const float* vp3 = ve + t3 * D + dim0;
      float4 va0 = *(const float4*)vp0, vb0 = *(const float4*)(vp0 + 4);
      float4 va1 = *(const float4*)vp1, vb1 = *(const float4*)(vp1 + 4);
      float4 va2 = *(const float4*)vp2, vb2 = *(const float4*)(vp2 + 4);
      float4 va3 = *(const float4*)vp3, vb3 = *(const float4*)(vp3 + 4);

      // q . k over lane's 8 dims (bf16 dot2), then head-reduce over 2 lanes
      float p0 = dot2bf(qp.x, ck0.x, dot2bf(qp.y, ck0.y, dot2bf(qp.z, ck0.z, dot2bf(qp.w, ck0.w, 0.f))));
      float p1 = dot2bf(qp.x, ck1.x, dot2bf(qp.y, ck1.y, dot2bf(qp.z, ck1.z, dot2bf(qp.w, ck1.w, 0.f))));
      float p2 = dot2bf(qp.x, ck2.x, dot2bf(qp.y, ck2.y, dot2bf(qp.z, ck2.z, dot2bf(qp.w, ck2.w, 0.f))));
      float p3 = dot2bf(qp.x, ck3.x, dot2bf(qp.y, ck3.y, dot2bf(qp.z, ck3.z, dot2bf(qp.w, ck3.w, 0.f))));
      p0 += __shfl_xor(p0, 1, 64);
      p1 += __shfl_xor(p1, 1, 64);
      p2 += __shfl_xor(p2, 1, 64);
      p3 += __shfl_xor(p3, 1, 64);

      float l0 = p0 + sel4(qk0, qk1, qk2, qk3, t0);
      float l1 = p1 + sel4(qk0, qk1, qk2, qk3, t1);
      float l2 = p2 + sel4(qk0, qk1, qk2, qk3, t2);
      float l3 = p3 + sel4(qk0, qk1, qk2, qk3, t3);
      l0 = l0 >= 0.f ? l0 : 0.2f * l0;
      l1 = l1 >= 0.f ? l1 : 0.2f * l1;
      l2 = l2 >= 0.f ? l2 : 0.2f * l2;
      l3 = l3 >= 0.f ? l3 : 0.2f * l3;
      if (n < 2) l1 = -INFINITY;
      if (n < 3) l2 = -INFINITY;
      if (n < 4) l3 = -INFINITY;
      float mb = fmaxf(fmaxf(l0, l1), fmaxf(l2, l3));
      float mn = fmaxf(m, mb);
      float f = __expf(m - mn);
      float a0 = __expf(l0 - mn);
      float a1 = __expf(l1 - mn);
      float a2 = __expf(l2 - mn);
      float a3 = __expf(l3 - mn);
      s = s * f + ((a0 + a1) + (a2 + a3));
      f32x2 ff = {f, f};
      acc01 *= ff; acc23 *= ff; acc45 *= ff; acc67 *= ff;
      f32x2 aa0 = {a0, a0}, aa1 = {a1, a1}, aa2 = {a2, a2}, aa3 = {a3, a3};
      acc01 = fma2(aa0, unpk(cv0.x) + (f32x2){va0.x, va0.y}, acc01);
      acc23 = fma2(aa0, unpk(cv0.y) + (f32x2){va0.z, va0.w}, acc23);
      acc45 = fma2(aa0, unpk(cv0.z) + (f32x2){vb0.x, vb0.y}, acc45);
      acc67 = fma2(aa0, unpk(cv0.w) + (f32x2){vb0.z, vb0.w}, acc67);
      acc01 = fma2(aa1, unpk(cv1.x) + (f32x2){va1.x, va1.y}, acc01);
      acc23 = fma2(aa1, unpk(cv1.y) + (f32x2){va1.z, va1.w}, acc23);
      acc45 = fma2(aa1, unpk(cv1.z) + (f32x2){vb1.x, vb1.y}, acc45);
      acc67 = fma2(aa1, unpk(cv1.w) + (f32x2){vb1.z, vb1.w}, acc67);
      acc01 = fma2(aa2, unpk(cv2.x) + (f32x2){va2.x, va2.y}, acc01);
      acc23 = fma2(aa2, unpk(cv2.y) + (f32x2){va2.z, va2.w}, acc23);
      acc45 = fma2(aa2, unpk(cv2.z) + (f32x2){vb2.x, vb2.y}, acc45);
      acc67 = fma2(aa2, unpk(cv2.w) + (f32x2){vb2.z, vb2.w}, acc67);
      acc01 = fma2(aa3, unpk(cv3.x) + (f32x2){va3.x, va3.y}, acc01);
      acc23 = fma2(aa3, unpk(cv3.y) + (f32x2){va3.z, va3.w}, acc23);
      acc45 = fma2(aa3, unpk(cv3.z) + (f32x2){vb3.x, vb3.y}, acc45);
      acc67 = fma2(aa3, unpk(cv3.w) + (f32x2){vb3.z, vb3.w}, acc67);
      m = mn;
    }
    cp0 = np0; cp1 = np1; cp2 = np2; cp3 = np3;
    ck0 = nk0; ck1 = nk1; ck2 = nk2; ck3 = nk3;
    j = jn;
  }
  if (active) {
    float inv = 1.f / (s + 1e-16f);
    float hf = 0.5f * inv;
    uint4 sk = *(const uint4*)(skipb + (size_t)d * D + dim0);
    f32x2 s0 = unpk(sk.x), s1 = unpk(sk.y), s2 = unpk(sk.z), s3 = unpk(sk.w);
    float* op = outp + (size_t)d * D + dim0;
    float4 o0, o1;
    o0.x = 0.5f * s0.x + hf * acc01.x;
    o0.y = 0.5f * s0.y + hf * acc01.y;
    o0.z = 0.5f * s1.x + hf * acc23.x;
    o0.w = 0.5f * s1.y + hf * acc23.y;
    o1.x = 0.5f * s2.x + hf * acc45.x;
    o1.y = 0.5f * s2.y + hf * acc45.y;
    o1.z = 0.5f * s3.x + hf * acc67.x;
    o1.w = 0.5f * s3.y + hf * acc67.y;
    *(float4*)op = o0;
    *(float4*)(op + 4) = o1;
  }
}

// ---------- batch norm ----------
__global__ __launch_bounds__(256) void bn_reduce(const float* __restrict__ h,
                                                 float* __restrict__ sums, int N) {
  int c = threadIdx.x & 127;
  int rofs = threadIdx.x >> 7;
  float s0 = 0.f, s1 = 0.f;
  for (int r = blockIdx.x * 2 + rofs; r < N; r += gridDim.x * 2) {
    float v = h[(size_t)r * 128 + c];
    s0 += v;
    s1 += v * v;
  }
  __shared__ float ls[256], lq[256];
  ls[threadIdx.x] = s0;
  lq[threadIdx.x] = s1;
  __syncthreads();
  if (threadIdx.x < 128) {
    atomicAdd(&sums[c], ls[threadIdx.x] + ls[threadIdx.x + 128]);
    atomicAdd(&sums[128 + c], lq[threadIdx.x] + lq[threadIdx.x + 128]);
  }
}

__global__ __launch_bounds__(256) void bn_apply(const float* __restrict__ h,
                                                u16* __restrict__ hbf,
                                                const float* __restrict__ sums,
                                                const float* __restrict__ gamma,
                                                const float* __restrict__ beta,
                                                float invN, int total) {
  __shared__ float sc[128], sh[128];
  int tid = threadIdx.x;
  if (tid < 128) {
    float mu = sums[tid] * invN;
    float var = sums[128 + tid] * invN - mu * mu;
    float inv = rsqrtf(var + 1e-5f);
    float s = gamma[tid] * inv;
    sc[tid] = s;
    sh[tid] = beta[tid] - mu * s;
  }
  __syncthreads();
  int i = blockIdx.x * 256 + tid;
  if (i < total) {
    int c = i & 127;
    hbf[i] = f2bf(h[i] * sc[c] + sh[c]);
  }
}

// ---------- launch ----------
extern "C" void kernel_launch(void* const* d_in, const int* in_sizes, int n_in,
                              void* d_out, int out_size, void* d_ws, size_t ws_size,
                              hipStream_t stream) {
  const float* x        = (const float*)d_in[0];
  const int*   ei0      = (const int*)d_in[1];
  const int*   et0      = (const int*)d_in[2];
  const int*   ei1      = (const int*)d_in[3];
  const int*   et1      = (const int*)d_in[4];
  const float* emb_type = (const float*)d_in[5];
  const float* emb_attr = (const float*)d_in[6];
  const float* v2e_Wq   = (const float*)d_in[7];
  const float* v2e_Wk   = (const float*)d_in[8];
  const float* v2e_Wv   = (const float*)d_in[9];
  const float* v2e_We   = (const float*)d_in[10];
  const float* v2e_Wsk  = (const float*)d_in[11];
  const float* e2_Wq    = (const float*)d_in[12];
  const float* e2_Wk    = (const float*)d_in[13];
  const float* e2_Wv    = (const float*)d_in[14];
  const float* e2_We    = (const float*)d_in[15];
  const float* e2_Wsk   = (const float*)d_in[16];
  const float* bn_gamma = (const float*)d_in[17];
  const float* bn_beta  = (const float*)d_in[18];
  float* out = (float*)d_out;

  // workspace layout
  char* wsb = (char*)d_ws;
  size_t off = 0;
  u16* xb  = (u16*)(wsb + off);  off += (size_t)NSRC * D * 2;
  u16* KVb = (u16*)(wsb + off);  off += (size_t)NSRC * D * 2 * 2;  // interleaved K|V
  u16* Qb  = (u16*)(wsb + off);  off += (size_t)NE0 * D * 2;
  u16* Sb  = (u16*)(wsb + off);  off += (size_t)NE0 * D * 2;
  float* hb = (float*)(wsb + off); off += (size_t)NE0 * D * 4;
  u16* hbf = (u16*)(wsb + off);  off += (size_t)NE0 * D * 2;
  u16* wtAll = (u16*)(wsb + off); off += 8 * 16384 * 2;
  int* elist = (int*)(wsb + off);  off += (size_t)ET * 4;
  int* rank  = (int*)(wsb + off);  off += (size_t)ET * 4;
  int* offs  = (int*)(wsb + off);  off += ((size_t)NT + 8) * 4;
  int* bsums = (int*)(wsb + off);  off += 1024;
  float* kv  = (float*)(wsb + off); off += 4 * 512 * 4;
  float* bnsums = (float*)(wsb + off); off += 256 * 4;  // sum[128] | sumsq[128]

  u16* wtK0 = wtAll + 0 * 16384;
  u16* wtV0 = wtAll + 1 * 16384;
  u16* wtQ0 = wtAll + 2 * 16384;
  u16* wtS0 = wtAll + 3 * 16384;
  u16* wtK1 = wtAll + 4 * 16384;
  u16* wtV1 = wtAll + 5 * 16384;
  u16* wtQ1 = wtAll + 6 * 16384;
  u16* wtS1 = wtAll + 7 * 16384;
  float* kep0 = kv;
  float* vep0 = kv + 512;
  float* kep1 = kv + 1024;
  float* vep1 = kv + 1536;

  const int* src0 = ei0;
  const int* dst0 = ei0 + E0N;
  const int* src1 = ei1;
  const int* dst1 = ei1 + E1N;

  // 1: mega-prep (cast + weights + embs + zeroing)
  prep_all<<<BC + 64 + 4 + BZ + 1, 256, 0, stream>>>(
      x, xb, v2e_Wk, v2e_Wv, v2e_Wq, v2e_Wsk, e2_Wk, e2_Wv, e2_Wq, e2_Wsk,
      wtAll, emb_type, emb_attr, v2e_We, e2_We, kv, offs, bnsums);

  // 2-6: CSR for both layers
  csr_count2<<<(ET + 255) / 256, 256, 0, stream>>>(dst0, dst1, offs, rank);
  {
    int nb = (NT + 1023) / 1024;
    scan1<<<nb, 256, 0, stream>>>(offs, offs, bsums, NT);
    scan2<<<1, 256, 0, stream>>>(bsums, nb);
    scan3<<<(NT + 255) / 256, 256, 0, stream>>>(offs, bsums, NT, ET);
  }
  csr_fill2<<<(ET + 255) / 256, 256, 0, stream>>>(dst0, src0, et0, dst1, src1, et1,
                                                  offs, rank, elist);

  // 7-10: layer 0
  {
    int nKV = (NSRC + 127) / 128, nQS = (NE0 + 127) / 128;
    gemm_quad<<<nKV + nQS, 256, 0, stream>>>(xb, wtK0, wtV0, KVb, NSRC, nKV,
                                             wtQ0, wtS0, Qb, Sb, NE0);
  }
  attn_fused<<<(NE0 + 15) / 16, 256, 0, stream>>>(elist, offs, Qb, KVb, kep0, vep0,
                                                  Sb, hb, NE0);
  bn_reduce<<<256, 256, 0, stream>>>(hb, bnsums, NE0);
  bn_apply<<<(NE0 * D + 255) / 256, 256, 0, stream>>>(hb, hbf, bnsums, bn_gamma, bn_beta,
                                                      1.0f / (float)NE0, NE0 * D);

  // 11-12: layer 1
  {
    int nKV = (NE0 + 127) / 128, nQS = (NE1 + 127) / 128;
    gemm_quad<<<nKV + nQS, 256, 0, stream>>>(hbf, wtK1, wtV1, KVb, NE0, nKV,
                                             wtQ1, wtS1, Qb, Sb, NE1);
  }
  attn_fused<<<(NE1 + 15) / 16, 256, 0, stream>>>(elist, offs + NE0, Qb, KVb, kep1, vep1,
                                                  Sb, out, NE1);
}

// Round 3
// 747.152 us; speedup vs baseline: 1.0549x; 1.0549x over previous
//
#include <hip/hip_runtime.h>
#include <cstdint>
#include <cstddef>

#define D 128
#define H 8
#define NSRC 200000
#define NE0  100000
#define NE1  50000
#define E0N  1000000
#define E1N  500000
#define NT   (NE0 + NE1)
#define ET   (E0N + E1N)

typedef unsigned short u16;
typedef __attribute__((ext_vector_type(8))) short short8;
typedef __attribute__((ext_vector_type(4))) float f32x4;
typedef __attribute__((ext_vector_type(2))) float f32x2;

// ---------- bf16 helpers ----------
__device__ __forceinline__ u16 f2bf(float f) {
  unsigned u = __float_as_uint(f);
  unsigned r = (u + 0x7fffu + ((u >> 16) & 1u)) >> 16;  // RNE
  return (u16)r;
}
__device__ __forceinline__ float bf2f(u16 u) {
  return __uint_as_float(((unsigned)u) << 16);
}
// unpack 2 packed bf16 (low = even dim) -> f32x2
__device__ __forceinline__ f32x2 unpk(unsigned u) {
  f32x2 r;
  r.x = __uint_as_float(u << 16);
  r.y = __uint_as_float(u & 0xffff0000u);
  return r;
}
// bf16 pair dot with f32 accumulate: d = a.lo*b.lo + a.hi*b.hi + c
__device__ __forceinline__ float dot2bf(unsigned a, unsigned b, float c) {
  float d;
  asm("v_dot2_f32_bf16 %0, %1, %2, %3" : "=v"(d) : "v"(a), "v"(b), "v"(c));
  return d;
}
__device__ __forceinline__ f32x2 fma2(f32x2 a, f32x2 b, f32x2 c) {
  return __builtin_elementwise_fma(a, b, c);
}

// ---------- mega-prep: x cast + weight transpose + emb GEMMs + zero-fill ----------
// block roles: [0,BC) cast | [BC,BC+64) weights | +4 embs | +BZ zero offs | +1 zero bn
#define BC 25000            // (NSRC*D/4)/256
#define BZ 147              // ceil((NT+1)/1024)
static_assert((size_t)BZ * 1024 >= NT + 1, "offs zero-fill must cover NT+1 entries");
__global__ __launch_bounds__(256) void prep_all(
    const float* __restrict__ x, u16* __restrict__ xb,
    const float* w0, const float* w1, const float* w2, const float* w3,
    const float* w4, const float* w5, const float* w6, const float* w7,
    u16* __restrict__ wt,
    const float* __restrict__ embA, const float* __restrict__ embB,
    const float* __restrict__ We0, const float* __restrict__ We1,
    float* __restrict__ kv,
    int* __restrict__ offs, float* __restrict__ bnsums) {
  int b = blockIdx.x;
  if (b < BC) {
    int i = b * 256 + threadIdx.x;
    float4 a = ((const float4*)x)[i];
    ushort4 o;
    o.x = f2bf(a.x); o.y = f2bf(a.y); o.z = f2bf(a.z); o.w = f2bf(a.w);
    ((ushort4*)xb)[i] = o;
  } else if (b < BC + 64) {
    int bb = b - BC;
    const float* wsrc[8] = {w0, w1, w2, w3, w4, w5, w6, w7};
    int mat = bb >> 3;
    int blk = bb & 7;
    const float* W = wsrc[mat];
    // fold 1/sqrt(d)=0.25 into Wq (mats 2 and 6) so Q comes out pre-scaled
    float sc = ((mat & 3) == 2) ? 0.25f : 1.0f;
    u16* out = wt + mat * 16384;
    for (int i = blk * 2048 + threadIdx.x; i < (blk + 1) * 2048; i += 256) {
      int n = i >> 7, k = i & 127;
      out[i] = f2bf(W[k * 128 + n] * sc);
    }
  } else if (b < BC + 68) {
    int bb = b - BC - 64;
    int mat = bb >> 1;
    int t = (bb & 1) * 256 + threadIdx.x;
    const float* We = mat ? We1 : We0;
    float* keOut = kv + mat * 1024;
    float* veOut = keOut + 512;
    int r = t >> 7, c = t & 127;
    float s0 = 0.f, s1 = 0.f;
    for (int k = 0; k < 128; ++k) {
      float w = We[k * 128 + c];
      s0 += embA[r * 128 + k] * w;
      s1 += embB[r * 128 + k] * w;
    }
    keOut[t] = s0;
    veOut[t] = s1;
  } else if (b < BC + 68 + BZ) {
    int base = (b - BC - 68) * 1024 + threadIdx.x * 4;
#pragma unroll
    for (int i = 0; i < 4; ++i)
      if (base + i < NT + 1) offs[base + i] = 0;
  } else {
    bnsums[threadIdx.x] = 0.f;  // 256 floats = bnsum|bnsq
  }
}

// ---------- quad-output MFMA GEMM (operand-swapped, feature-split) ----------
// Latency-bound fix (R2): acc[2][2][8]=128 VGPR forced 2 waves/SIMD (occupancy
// 10%, all pipes idle). Split the 128-feature tile across TWO blocks (fh =
// blockIdx&1 selects a 64-feature half): acc[2][2][4]=64 VGPR +
// __launch_bounds__(256,4) -> 4 waves/SIMD. Paired blocks share A rows
// (adjacent dispatch -> same XCD L2 hit).
// mfma(b, a, acc): lane owns one data row, acc regs = 4 consecutive features
// -> packed 8B stores, no partial-sector write amp.
__global__ __launch_bounds__(256, 4) void gemm_quad(
    const u16* __restrict__ A,
    const u16* __restrict__ WtK, const u16* __restrict__ WtV,
    u16* __restrict__ CKV, int NA, int nKV,
    const u16* __restrict__ WtQ, const u16* __restrict__ WtS,
    u16* __restrict__ CQ, u16* __restrict__ CS, int NB) {
  int fh = blockIdx.x & 1;        // feature half: j-tiles [fh*4, fh*4+4)
  int bb = blockIdx.x >> 1;
  const u16 *Wt0, *Wt1;
  int N, row0;
  bool ilv = (bb < nKV);
  if (ilv) {
    Wt0 = WtK; Wt1 = WtV; N = NA; row0 = bb * 128;
  } else {
    Wt0 = WtQ; Wt1 = WtS; N = NB; row0 = (bb - nKV) * 128;
  }
  int w = threadIdx.x >> 6, lane = threadIdx.x & 63;
  int lrow = lane & 15, q = lane >> 4;
  row0 += w * 32;
  int ra = row0 + lrow;
  int rb = row0 + 16 + lrow;
  const u16* WB0 = Wt0 + fh * 4 * 16 * 128;  // this half's first weight row
  const u16* WB1 = Wt1 + fh * 4 * 16 * 128;

  f32x4 acc[2][2][4];
#pragma unroll
  for (int o = 0; o < 2; ++o)
#pragma unroll
    for (int i = 0; i < 2; ++i)
#pragma unroll
      for (int j = 0; j < 4; ++j) acc[o][i][j] = (f32x4){0.f, 0.f, 0.f, 0.f};

  const short8 zero8 = {0, 0, 0, 0, 0, 0, 0, 0};
#pragma unroll
  for (int kk = 0; kk < 128; kk += 32) {
    int ko = kk + q * 8;
    short8 a0 = (ra < N) ? *(const short8*)(A + (size_t)ra * 128 + ko) : zero8;
    short8 a1 = (rb < N) ? *(const short8*)(A + (size_t)rb * 128 + ko) : zero8;
#pragma unroll
    for (int j = 0; j < 4; ++j) {
      short8 b0 = *(const short8*)(WB0 + (j * 16 + lrow) * 128 + ko);
      short8 b1 = *(const short8*)(WB1 + (j * 16 + lrow) * 128 + ko);
      // swapped operands: D^T mapping (lane&15 = data row, regs = 4 features)
      acc[0][0][j] = __builtin_amdgcn_mfma_f32_16x16x32_bf16(b0, a0, acc[0][0][j], 0, 0, 0);
      acc[0][1][j] = __builtin_amdgcn_mfma_f32_16x16x32_bf16(b0, a1, acc[0][1][j], 0, 0, 0);
      acc[1][0][j] = __builtin_amdgcn_mfma_f32_16x16x32_bf16(b1, a0, acc[1][0][j], 0, 0, 0);
      acc[1][1][j] = __builtin_amdgcn_mfma_f32_16x16x32_bf16(b1, a1, acc[1][1][j], 0, 0, 0);
    }
  }
  // epilogue: lane owns row (row0 + i*16 + lrow); features f = jj*16 + q*4 + r
  if (ilv) {
#pragma unroll
    for (int i = 0; i < 2; ++i) {
      int grow = row0 + i * 16 + lrow;
      if (grow < N) {
#pragma unroll
        for (int o = 0; o < 2; ++o) {
          // f>>3 = 2jj + (q>>1); f&7 = (q&1)*4 + r
          u16* base = CKV + (size_t)grow * 256 + (o << 3) + ((q & 1) << 2) + ((q >> 1) << 4)
                      + fh * 4 * 32;
#pragma unroll
          for (int j = 0; j < 4; ++j) {
            f32x4 v = acc[o][i][j];
            ushort4 pk;
            pk.x = f2bf(v[0]); pk.y = f2bf(v[1]); pk.z = f2bf(v[2]); pk.w = f2bf(v[3]);
            *(ushort4*)(base + j * 32) = pk;
          }
        }
      }
    }
  } else {
#pragma unroll
    for (int o = 0; o < 2; ++o) {
      u16* C = o ? CS : CQ;
#pragma unroll
      for (int i = 0; i < 2; ++i) {
        int grow = row0 + i * 16 + lrow;
        if (grow < N) {
          u16* base = C + (size_t)grow * 128 + q * 4 + fh * 4 * 16;
#pragma unroll
          for (int j = 0; j < 4; ++j) {
            f32x4 v = acc[o][i][j];
            ushort4 pk;
            pk.x = f2bf(v[0]); pk.y = f2bf(v[1]); pk.z = f2bf(v[2]); pk.w = f2bf(v[3]);
            *(ushort4*)(base + j * 16) = pk;
          }
        }
      }
    }
  }
}

// ---------- CSR build (both layers, rank-based fill) ----------
__global__ __launch_bounds__(256) void csr_count2(
    const int* __restrict__ dst0, const int* __restrict__ dst1,
    int* __restrict__ cnt, int* __restrict__ rank) {
  int t = blockIdx.x * 256 + threadIdx.x;
  if (t < E0N) {
    rank[t] = atomicAdd(&cnt[dst0[t]], 1);
  } else if (t < ET) {
    rank[t] = atomicAdd(&cnt[NE0 + dst1[t - E0N]], 1);
  }
}

__global__ __launch_bounds__(256) void scan1(const int* __restrict__ cnt,
                                             int* __restrict__ excl,
                                             int* __restrict__ blocksums, int N) {
  __shared__ int sh[256];
  int tid = threadIdx.x;
  int base = blockIdx.x * 1024 + tid * 4;
  int v0 = (base + 0 < N) ? cnt[base + 0] : 0;
  int v1 = (base + 1 < N) ? cnt[base + 1] : 0;
  int v2 = (base + 2 < N) ? cnt[base + 2] : 0;
  int v3 = (base + 3 < N) ? cnt[base + 3] : 0;
  int tsum = v0 + v1 + v2 + v3;
  sh[tid] = tsum;
  __syncthreads();
  for (int off = 1; off < 256; off <<= 1) {
    int t2 = (tid >= off) ? sh[tid - off] : 0;
    __syncthreads();
    sh[tid] += t2;
    __syncthreads();
  }
  int incl = sh[tid];
  if (tid == 255) blocksums[blockIdx.x] = incl;
  int run = incl - tsum;
  if (base + 0 < N) excl[base + 0] = run; run += v0;
  if (base + 1 < N) excl[base + 1] = run; run += v1;
  if (base + 2 < N) excl[base + 2] = run; run += v2;
  if (base + 3 < N) excl[base + 3] = run;
}

__global__ void scan2(int* __restrict__ blocksums, int nb) {
  __shared__ int sh[256];
  int tid = threadIdx.x;
  int v = (tid < nb) ? blocksums[tid] : 0;
  sh[tid] = v;
  __syncthreads();
  for (int off = 1; off < 256; off <<= 1) {
    int t2 = (tid >= off) ? sh[tid - off] : 0;
    __syncthreads();
    sh[tid] += t2;
    __syncthreads();
  }
  if (tid < nb) blocksums[tid] = sh[tid] - v;
}

__global__ __launch_bounds__(256) void scan3(int* __restrict__ offs,
                                             const int* __restrict__ blocksums, int N,
                                             int Etot) {
  int t = blockIdx.x * 256 + threadIdx.x;
  if (t < N) offs[t] += blocksums[t >> 10];
  if (t == 0) offs[N] = Etot;
}

__global__ __launch_bounds__(256) void csr_fill2(
    const int* __restrict__ dst0, const int* __restrict__ src0, const int* __restrict__ et0,
    const int* __restrict__ dst1, const int* __restrict__ src1, const int* __restrict__ et1,
    const int* __restrict__ offs, const int* __restrict__ rank,
    int* __restrict__ elist) {
  int t = blockIdx.x * 256 + threadIdx.x;
  if (t < E0N) {
    int p = offs[dst0[t]] + rank[t];
    elist[p] = (src0[t] << 2) | et0[t];
  } else if (t < ET) {
    int t2 = t - E0N;
    int p = offs[NE0 + dst1[t2]] + rank[t];
    elist[p] = (src1[t2] << 2) | et1[t2];
  }
}

// ---------- fused flash attention + skip combine ----------
// 4 dsts/wave, 16 lanes/dst, 8 consecutive dims/lane.
// KV table is interleaved: row = 16 groups of {K[8] | V[8]} bf16.
// Q pre-scaled by 0.25 (folded into Wq).
__device__ __forceinline__ float sel4(float s0, float s1, float s2, float s3, int ty) {
  float a = (ty & 1) ? s1 : s0;
  float b = (ty & 1) ? s3 : s2;
  return (ty & 2) ? b : a;
}

__global__ __launch_bounds__(256) void attn_fused(
    const int* __restrict__ elist, const int* __restrict__ offs,
    const u16* __restrict__ Q, const u16* __restrict__ KV,
    const float* __restrict__ ke, const float* __restrict__ ve,
    const u16* __restrict__ skipb, float* __restrict__ outp, int N) {
  int wave = (blockIdx.x * 256 + threadIdx.x) >> 6;
  int lane = threadIdx.x & 63;
  int which = lane >> 4;   // dst slot within wave
  int sub = lane & 15;     // 16 lanes per dst
  int d = wave * 4 + which;
  bool active = d < N;
  int dc = active ? d : 0;
  int dim0 = sub * 8;      // 8 consecutive dims per lane; head = sub>>1
  int sub16 = sub * 16;    // u16 offset of this lane's group within a KV row

  // Q: 8 dims as 4 packed bf16 pairs (already scaled by 1/sqrt(d))
  uint4 qp = *(const uint4*)(Q + (size_t)dc * D + dim0);
  f32x2 u0 = unpk(qp.x), u1 = unpk(qp.y), u2 = unpk(qp.z), u3 = unpk(qp.w);

  // per-type q . (We ek) : reduce over head (2 lanes)
  float qk0, qk1, qk2, qk3;
#pragma unroll
  for (int ty = 0; ty < 4; ++ty) {
    const float* kt = ke + ty * D + dim0;
    float4 ka = *(const float4*)kt;
    float4 kb = *(const float4*)(kt + 4);
    float p = u0.x * ka.x + u0.y * ka.y + u1.x * ka.z + u1.y * ka.w +
              u2.x * kb.x + u2.y * kb.y + u3.x * kb.z + u3.y * kb.w;
    p += __shfl_xor(p, 1, 64);
    if (ty == 0) qk0 = p; else if (ty == 1) qk1 = p; else if (ty == 2) qk2 = p; else qk3 = p;
  }

  int j0 = active ? offs[d] : 0;
  int j1 = active ? offs[d + 1] : 0;
  int j = j0;

  // prefetched current batch: edge codes + K-part rows
  int cp0, cp1, cp2, cp3;
  uint4 ck0, ck1, ck2, ck3;
  {
    int i0 = (j + 0 < j1) ? j + 0 : 0;
    int i1 = (j + 1 < j1) ? j + 1 : 0;
    int i2 = (j + 2 < j1) ? j + 2 : 0;
    int i3 = (j + 3 < j1) ? j + 3 : 0;
    cp0 = elist[i0]; cp1 = elist[i1]; cp2 = elist[i2]; cp3 = elist[i3];
    ck0 = *(const uint4*)(KV + (size_t)(cp0 >> 2) * 256 + sub16);
    ck1 = *(const uint4*)(KV + (size_t)(cp1 >> 2) * 256 + sub16);
    ck2 = *(const uint4*)(KV + (size_t)(cp2 >> 2) * 256 + sub16);
    ck3 = *(const uint4*)(KV + (size_t)(cp3 >> 2) * 256 + sub16);
  }

  float m = -INFINITY, s = 0.f;
  f32x2 acc01 = {0.f, 0.f}, acc23 = {0.f, 0.f}, acc45 = {0.f, 0.f}, acc67 = {0.f, 0.f};

  while (__any(j < j1)) {
    int jn = j + 4;
    // prefetch next batch (K-part only; clamped)
    int i0 = (jn + 0 < j1) ? jn + 0 : 0;
    int i1 = (jn + 1 < j1) ? jn + 1 : 0;
    int i2 = (jn + 2 < j1) ? jn + 2 : 0;
    int i3 = (jn + 3 < j1) ? jn + 3 : 0;
    int np0 = elist[i0], np1 = elist[i1], np2 = elist[i2], np3 = elist[i3];
    uint4 nk0 = *(const uint4*)(KV + (size_t)(np0 >> 2) * 256 + sub16);
    uint4 nk1 = *(const uint4*)(KV + (size_t)(np1 >> 2) * 256 + sub16);
    uint4 nk2 = *(const uint4*)(KV + (size_t)(np2 >> 2) * 256 + sub16);
    uint4 nk3 = *(const uint4*)(KV + (size_t)(np3 >> 2) * 256 + sub16);

    int n = j1 - j;
    if (n > 0) {
      int t0 = cp0 & 3, t1 = cp1 & 3, t2 = cp2 & 3, t3 = cp3 & 3;
      // issue V-part + type-table loads early (addrs ready from prefetch)
      uint4 cv0 = *(const uint4*)(KV + (size_t)(cp0 >> 2) * 256 + sub16 + 8);
      uint4 cv1 = *(const uint4*)(KV + (size_t)(cp1 >> 2) * 256 + sub16 + 8);
      uint4 cv2 = *(const uint4*)(KV + (size_t)(cp2 >> 2) * 256 + sub16 + 8);
      uint4 cv3 = *(const uint4*)(KV + (size_t)(cp3 >> 2) * 256 + sub16 + 8);
      const float* vp0 = ve + t0 * D + dim0;
      const float* vp1 = ve + t1 * D + dim0;
      const float* vp2 = ve + t2 * D + dim0;
      const float* vp3 = ve + t3 * D + dim0;
      float4 va0 = *(const float4*)vp0, vb0 = *(const float4*)(vp0 + 4);
      float4 va1 = *(const float4*)vp1, vb1 = *(const float4*)(vp1 + 4);
      float4 va2 = *(const float4*)vp2, vb2 = *(const float4*)(vp2 + 4);
      float4 va3 = *(const float4*)vp3, vb3 = *(const float4*)(vp3 + 4);

      // q . k over lane's 8 dims (bf16 dot2), then head-reduce over 2 lanes
      float p0 = dot2bf(qp.x, ck0.x, dot2bf(qp.y, ck0.y, dot2bf(qp.z, ck0.z, dot2bf(qp.w, ck0.w, 0.f))));
      float p1 = dot2bf(qp.x, ck1.x, dot2bf(qp.y, ck1.y, dot2bf(qp.z, ck1.z, dot2bf(qp.w, ck1.w, 0.f))));
      float p2 = dot2bf(qp.x, ck2.x, dot2bf(qp.y, ck2.y, dot2bf(qp.z, ck2.z, dot2bf(qp.w, ck2.w, 0.f))));
      float p3 = dot2bf(qp.x, ck3.x, dot2bf(qp.y, ck3.y, dot2bf(qp.z, ck3.z, dot2bf(qp.w, ck3.w, 0.f))));
      p0 += __shfl_xor(p0, 1, 64);
      p1 += __shfl_xor(p1, 1, 64);
      p2 += __shfl_xor(p2, 1, 64);
      p3 += __shfl_xor(p3, 1, 64);

      float l0 = p0 + sel4(qk0, qk1, qk2, qk3, t0);
      float l1 = p1 + sel4(qk0, qk1, qk2, qk3, t1);
      float l2 = p2 + sel4(qk0, qk1, qk2, qk3, t2);
      float l3 = p3 + sel4(qk0, qk1, qk2, qk3, t3);
      l0 = l0 >= 0.f ? l0 : 0.2f * l0;
      l1 = l1 >= 0.f ? l1 : 0.2f * l1;
      l2 = l2 >= 0.f ? l2 : 0.2f * l2;
      l3 = l3 >= 0.f ? l3 : 0.2f * l3;
      if (n < 2) l1 = -INFINITY;
      if (n < 3) l2 = -INFINITY;
      if (n < 4) l3 = -INFINITY;
      float mb = fmaxf(fmaxf(l0, l1), fmaxf(l2, l3));
      float mn = fmaxf(m, mb);
      float f = __expf(m - mn);
      float a0 = __expf(l0 - mn);
      float a1 = __expf(l1 - mn);
      float a2 = __expf(l2 - mn);
      float a3 = __expf(l3 - mn);
      s = s * f + ((a0 + a1) + (a2 + a3));
      f32x2 ff = {f, f};
      acc01 *= ff; acc23 *= ff; acc45 *= ff; acc67 *= ff;
      f32x2 aa0 = {a0, a0}, aa1 = {a1, a1}, aa2 = {a2, a2}, aa3 = {a3, a3};
      acc01 = fma2(aa0, unpk(cv0.x) + (f32x2){va0.x, va0.y}, acc01);
      acc23 = fma2(aa0, unpk(cv0.y) + (f32x2){va0.z, va0.w}, acc23);
      acc45 = fma2(aa0, unpk(cv0.z) + (f32x2){vb0.x, vb0.y}, acc45);
      acc67 = fma2(aa0, unpk(cv0.w) + (f32x2){vb0.z, vb0.w}, acc67);
      acc01 = fma2(aa1, unpk(cv1.x) + (f32x2){va1.x, va1.y}, acc01);
      acc23 = fma2(aa1, unpk(cv1.y) + (f32x2){va1.z, va1.w}, acc23);
      acc45 = fma2(aa1, unpk(cv1.z) + (f32x2){vb1.x, vb1.y}, acc45);
      acc67 = fma2(aa1, unpk(cv1.w) + (f32x2){vb1.z, vb1.w}, acc67);
      acc01 = fma2(aa2, unpk(cv2.x) + (f32x2){va2.x, va2.y}, acc01);
      acc23 = fma2(aa2, unpk(cv2.y) + (f32x2){va2.z, va2.w}, acc23);
      acc45 = fma2(aa2, unpk(cv2.z) + (f32x2){vb2.x, vb2.y}, acc45);
      acc67 = fma2(aa2, unpk(cv2.w) + (f32x2){vb2.z, vb2.w}, acc67);
      acc01 = fma2(aa3, unpk(cv3.x) + (f32x2){va3.x, va3.y}, acc01);
      acc23 = fma2(aa3, unpk(cv3.y) + (f32x2){va3.z, va3.w}, acc23);
      acc45 = fma2(aa3, unpk(cv3.z) + (f32x2){vb3.x, vb3.y}, acc45);
      acc67 = fma2(aa3, unpk(cv3.w) + (f32x2){vb3.z, vb3.w}, acc67);
      m = mn;
    }
    cp0 = np0; cp1 = np1; cp2 = np2; cp3 = np3;
    ck0 = nk0; ck1 = nk1; ck2 = nk2; ck3 = nk3;
    j = jn;
  }
  if (active) {
    float inv = 1.f / (s + 1e-16f);
    float hf = 0.5f * inv;
    uint4 sk = *(const uint4*)(skipb + (size_t)d * D + dim0);
    f32x2 s0 = unpk(sk.x), s1 = unpk(sk.y), s2 = unpk(sk.z), s3 = unpk(sk.w);
    float* op = outp + (size_t)d * D + dim0;
    float4 o0, o1;
    o0.x = 0.5f * s0.x + hf * acc01.x;
    o0.y = 0.5f * s0.y + hf * acc01.y;
    o0.z = 0.5f * s1.x + hf * acc23.x;
    o0.w = 0.5f * s1.y + hf * acc23.y;
    o1.x = 0.5f * s2.x + hf * acc45.x;
    o1.y = 0.5f * s2.y + hf * acc45.y;
    o1.z = 0.5f * s3.x + hf * acc67.x;
    o1.w = 0.5f * s3.y + hf * acc67.y;
    *(float4*)op = o0;
    *(float4*)(op + 4) = o1;
  }
}

// ---------- batch norm ----------
__global__ __launch_bounds__(256) void bn_reduce(const float* __restrict__ h,
                                                 float* __restrict__ sums, int N) {
  int c = threadIdx.x & 127;
  int rofs = threadIdx.x >> 7;
  float s0 = 0.f, s1 = 0.f;
  for (int r = blockIdx.x * 2 + rofs; r < N; r += gridDim.x * 2) {
    float v = h[(size_t)r * 128 + c];
    s0 += v;
    s1 += v * v;
  }
  __shared__ float ls[256], lq[256];
  ls[threadIdx.x] = s0;
  lq[threadIdx.x] = s1;
  __syncthreads();
  if (threadIdx.x < 128) {
    atomicAdd(&sums[c], ls[threadIdx.x] + ls[threadIdx.x + 128]);
    atomicAdd(&sums[128 + c], lq[threadIdx.x] + lq[threadIdx.x + 128]);
  }
}

__global__ __launch_bounds__(256) void bn_apply(const float* __restrict__ h,
                                                u16* __restrict__ hbf,
                                                const float* __restrict__ sums,
                                                const float* __restrict__ gamma,
                                                const float* __restrict__ beta,
                                                float invN, int total) {
  __shared__ float sc[128], sh[128];
  int tid = threadIdx.x;
  if (tid < 128) {
    float mu = sums[tid] * invN;
    float var = sums[128 + tid] * invN - mu * mu;
    float inv = rsqrtf(var + 1e-5f);
    float s = gamma[tid] * inv;
    sc[tid] = s;
    sh[tid] = beta[tid] - mu * s;
  }
  __syncthreads();
  int i = blockIdx.x * 256 + tid;
  if (i < total) {
    int c = i & 127;
    hbf[i] = f2bf(h[i] * sc[c] + sh[c]);
  }
}

// ---------- launch ----------
extern "C" void kernel_launch(void* const* d_in, const int* in_sizes, int n_in,
                              void* d_out, int out_size, void* d_ws, size_t ws_size,
                              hipStream_t stream) {
  const float* x        = (const float*)d_in[0];
  const int*   ei0      = (const int*)d_in[1];
  const int*   et0      = (const int*)d_in[2];
  const int*   ei1      = (const int*)d_in[3];
  const int*   et1      = (const int*)d_in[4];
  const float* emb_type = (const float*)d_in[5];
  const float* emb_attr = (const float*)d_in[6];
  const float* v2e_Wq   = (const float*)d_in[7];
  const float* v2e_Wk   = (const float*)d_in[8];
  const float* v2e_Wv   = (const float*)d_in[9];
  const float* v2e_We   = (const float*)d_in[10];
  const float* v2e_Wsk  = (const float*)d_in[11];
  const float* e2_Wq    = (const float*)d_in[12];
  const float* e2_Wk    = (const float*)d_in[13];
  const float* e2_Wv    = (const float*)d_in[14];
  const float* e2_We    = (const float*)d_in[15];
  const float* e2_Wsk   = (const float*)d_in[16];
  const float* bn_gamma = (const float*)d_in[17];
  const float* bn_beta  = (const float*)d_in[18];
  float* out = (float*)d_out;

  // workspace layout
  char* wsb = (char*)d_ws;
  size_t off = 0;
  u16* xb  = (u16*)(wsb + off);  off += (size_t)NSRC * D * 2;
  u16* KVb = (u16*)(wsb + off);  off += (size_t)NSRC * D * 2 * 2;  // interleaved K|V
  u16* Qb  = (u16*)(wsb + off);  off += (size_t)NE0 * D * 2;
  u16* Sb  = (u16*)(wsb + off);  off += (size_t)NE0 * D * 2;
  float* hb = (float*)(wsb + off); off += (size_t)NE0 * D * 4;
  u16* hbf = (u16*)(wsb + off);  off += (size_t)NE0 * D * 2;
  u16* wtAll = (u16*)(wsb + off); off += 8 * 16384 * 2;
  int* elist = (int*)(wsb + off);  off += (size_t)ET * 4;
  int* rank  = (int*)(wsb + off);  off += (size_t)ET * 4;
  int* offs  = (int*)(wsb + off);  off += ((size_t)NT + 8) * 4;
  int* bsums = (int*)(wsb + off);  off += 1024;
  float* kv  = (float*)(wsb + off); off += 4 * 512 * 4;
  float* bnsums = (float*)(wsb + off); off += 256 * 4;  // sum[128] | sumsq[128]

  u16* wtK0 = wtAll + 0 * 16384;
  u16* wtV0 = wtAll + 1 * 16384;
  u16* wtQ0 = wtAll + 2 * 16384;
  u16* wtS0 = wtAll + 3 * 16384;
  u16* wtK1 = wtAll + 4 * 16384;
  u16* wtV1 = wtAll + 5 * 16384;
  u16* wtQ1 = wtAll + 6 * 16384;
  u16* wtS1 = wtAll + 7 * 16384;
  float* kep0 = kv;
  float* vep0 = kv + 512;
  float* kep1 = kv + 1024;
  float* vep1 = kv + 1536;

  const int* src0 = ei0;
  const int* dst0 = ei0 + E0N;
  const int* src1 = ei1;
  const int* dst1 = ei1 + E1N;

  // 1: mega-prep (cast + weights + embs + zeroing)
  prep_all<<<BC + 64 + 4 + BZ + 1, 256, 0, stream>>>(
      x, xb, v2e_Wk, v2e_Wv, v2e_Wq, v2e_Wsk, e2_Wk, e2_Wv, e2_Wq, e2_Wsk,
      wtAll, emb_type, emb_attr, v2e_We, e2_We, kv, offs, bnsums);

  // 2-6: CSR for both layers
  csr_count2<<<(ET + 255) / 256, 256, 0, stream>>>(dst0, dst1, offs, rank);
  {
    int nb = (NT + 1023) / 1024;
    scan1<<<nb, 256, 0, stream>>>(offs, offs, bsums, NT);
    scan2<<<1, 256, 0, stream>>>(bsums, nb);
    scan3<<<(NT + 255) / 256, 256, 0, stream>>>(offs, bsums, NT, ET);
  }
  csr_fill2<<<(ET + 255) / 256, 256, 0, stream>>>(dst0, src0, et0, dst1, src1, et1,
                                                  offs, rank, elist);

  // 7-10: layer 0
  {
    int nKV = (NSRC + 127) / 128, nQS = (NE0 + 127) / 128;
    gemm_quad<<<2 * (nKV + nQS), 256, 0, stream>>>(xb, wtK0, wtV0, KVb, NSRC, nKV,
                                                   wtQ0, wtS0, Qb, Sb, NE0);
  }
  attn_fused<<<(NE0 + 15) / 16, 256, 0, stream>>>(elist, offs, Qb, KVb, kep0, vep0,
                                                  Sb, hb, NE0);
  bn_reduce<<<256, 256, 0, stream>>>(hb, bnsums, NE0);
  bn_apply<<<(NE0 * D + 255) / 256, 256, 0, stream>>>(hb, hbf, bnsums, bn_gamma, bn_beta,
                                                      1.0f / (float)NE0, NE0 * D);

  // 11-12: layer 1
  {
    int nKV = (NE0 + 127) / 128, nQS = (NE1 + 127) / 128;
    gemm_quad<<<2 * (nKV + nQS), 256, 0, stream>>>(hbf, wtK1, wtV1, KVb, NE0, nKV,
                                                   wtQ1, wtS1, Qb, Sb, NE1);
  }
  attn_fused<<<(NE1 + 15) / 16, 256, 0, stream>>>(elist, offs + NE0, Qb, KVb, kep1, vep1,
                                                  Sb, out, NE1);
}

// Round 4
// 731.966 us; speedup vs baseline: 1.0768x; 1.0207x over previous
//
#include <hip/hip_runtime.h>
#include <cstdint>
#include <cstddef>

#define D 128
#define H 8
#define NSRC 200000
#define NE0  100000
#define NE1  50000
#define E0N  1000000
#define E1N  500000
#define NT   (NE0 + NE1)
#define ET   (E0N + E1N)

typedef unsigned short u16;
typedef __attribute__((ext_vector_type(8))) short short8;
typedef __attribute__((ext_vector_type(4))) float f32x4;
typedef __attribute__((ext_vector_type(2))) float f32x2;

// ---------- bf16 helpers ----------
__device__ __forceinline__ u16 f2bf(float f) {
  unsigned u = __float_as_uint(f);
  unsigned r = (u + 0x7fffu + ((u >> 16) & 1u)) >> 16;  // RNE
  return (u16)r;
}
__device__ __forceinline__ float bf2f(u16 u) {
  return __uint_as_float(((unsigned)u) << 16);
}
// unpack 2 packed bf16 (low = even dim) -> f32x2
__device__ __forceinline__ f32x2 unpk(unsigned u) {
  f32x2 r;
  r.x = __uint_as_float(u << 16);
  r.y = __uint_as_float(u & 0xffff0000u);
  return r;
}
// bf16 pair dot with f32 accumulate: d = a.lo*b.lo + a.hi*b.hi + c
__device__ __forceinline__ float dot2bf(unsigned a, unsigned b, float c) {
  float d;
  asm("v_dot2_f32_bf16 %0, %1, %2, %3" : "=v"(d) : "v"(a), "v"(b), "v"(c));
  return d;
}
__device__ __forceinline__ f32x2 fma2(f32x2 a, f32x2 b, f32x2 c) {
  return __builtin_elementwise_fma(a, b, c);
}

// ---------- mega-prep: x cast + weight transpose + emb GEMMs + zero-fill ----------
// block roles: [0,BC) cast | [BC,BC+64) weights | +4 embs | +BZ zero offs | +1 zero bn
#define BC 25000            // (NSRC*D/4)/256
#define BZ 147              // ceil((NT+1)/1024)
static_assert((size_t)BZ * 1024 >= NT + 1, "offs zero-fill must cover NT+1 entries");
__global__ __launch_bounds__(256) void prep_all(
    const float* __restrict__ x, u16* __restrict__ xb,
    const float* w0, const float* w1, const float* w2, const float* w3,
    const float* w4, const float* w5, const float* w6, const float* w7,
    u16* __restrict__ wt,
    const float* __restrict__ embA, const float* __restrict__ embB,
    const float* __restrict__ We0, const float* __restrict__ We1,
    float* __restrict__ kv,
    int* __restrict__ offs, float* __restrict__ bnsums) {
  int b = blockIdx.x;
  if (b < BC) {
    int i = b * 256 + threadIdx.x;
    float4 a = ((const float4*)x)[i];
    ushort4 o;
    o.x = f2bf(a.x); o.y = f2bf(a.y); o.z = f2bf(a.z); o.w = f2bf(a.w);
    ((ushort4*)xb)[i] = o;
  } else if (b < BC + 64) {
    int bb = b - BC;
    const float* wsrc[8] = {w0, w1, w2, w3, w4, w5, w6, w7};
    int mat = bb >> 3;
    int blk = bb & 7;
    const float* W = wsrc[mat];
    // fold 1/sqrt(d)=0.25 into Wq (mats 2 and 6) so Q comes out pre-scaled
    float sc = ((mat & 3) == 2) ? 0.25f : 1.0f;
    u16* out = wt + mat * 16384;
    for (int i = blk * 2048 + threadIdx.x; i < (blk + 1) * 2048; i += 256) {
      int n = i >> 7, k = i & 127;
      out[i] = f2bf(W[k * 128 + n] * sc);
    }
  } else if (b < BC + 68) {
    int bb = b - BC - 64;
    int mat = bb >> 1;
    int t = (bb & 1) * 256 + threadIdx.x;
    const float* We = mat ? We1 : We0;
    float* keOut = kv + mat * 1024;
    float* veOut = keOut + 512;
    int r = t >> 7, c = t & 127;
    float s0 = 0.f, s1 = 0.f;
    for (int k = 0; k < 128; ++k) {
      float w = We[k * 128 + c];
      s0 += embA[r * 128 + k] * w;
      s1 += embB[r * 128 + k] * w;
    }
    keOut[t] = s0;
    veOut[t] = s1;
  } else if (b < BC + 68 + BZ) {
    int base = (b - BC - 68) * 1024 + threadIdx.x * 4;
#pragma unroll
    for (int i = 0; i < 4; ++i)
      if (base + i < NT + 1) offs[base + i] = 0;
  } else {
    bnsums[threadIdx.x] = 0.f;  // 256 floats = bnsum|bnsq
  }
}

// ---------- quad-output MFMA GEMM, LDS-staged (R4) ----------
// R3 post-mortem: occupancy fix alone left dur flat -> latency chain was the
// per-kk load->waitcnt->MFMA serialization (40 VMEM dests don't fit in 64
// VGPRs, compiler can't hoist). Fix: decouple load from compute. 512-thread
// block stages its 128-row x 128-k A-tile (32 KB) in LDS ONCE (coalesced,
// one barrier), then all 8 waves compute from LDS. Feature split is now
// INTRA-block (h = wave&1) so A is read from HBM exactly once (no fh re-read).
// LDS chunk-XOR swizzle (chunk ^= row&15) spreads the stride-256B fragment
// reads across all bank quads (G4).
// mfma(b, a, acc): lane owns one data row, acc regs = 4 consecutive features
// -> packed 8B stores, full line coverage.
__global__ __launch_bounds__(512, 4) void gemm_quad(
    const u16* __restrict__ A,
    const u16* __restrict__ WtK, const u16* __restrict__ WtV,
    u16* __restrict__ CKV, int NA, int nKV,
    const u16* __restrict__ WtQ, const u16* __restrict__ WtS,
    u16* __restrict__ CQ, u16* __restrict__ CS, int NB) {
  int bb = blockIdx.x;
  const u16 *Wt0, *Wt1;
  int N, tile0;
  bool ilv = (bb < nKV);
  if (ilv) {
    Wt0 = WtK; Wt1 = WtV; N = NA; tile0 = bb * 128;
  } else {
    Wt0 = WtQ; Wt1 = WtS; N = NB; tile0 = (bb - nKV) * 128;
  }
  int tid = threadIdx.x;
  int w = tid >> 6, lane = tid & 63;
  int g = w >> 1;          // row group: rows [g*32, g*32+32)
  int h = w & 1;           // feature half: features [h*64, h*64+64)
  int lrow = lane & 15, q = lane >> 4;

  // ---- stage A tile: global (linear, coalesced) -> LDS (chunk-XOR swizzled)
  // LDS(row, c) = global(row, c ^ (row&15)); 16B chunks, 16 chunks/row.
  __shared__ u16 Als[128 * 128];  // 32 KB
  {
    const u16* gsrc = A + (size_t)tile0 * 128;
    uint4 t0 = *(const uint4*)(gsrc + (0 * 512 + tid) * 8);
    uint4 t1 = *(const uint4*)(gsrc + (1 * 512 + tid) * 8);
    uint4 t2 = *(const uint4*)(gsrc + (2 * 512 + tid) * 8);
    uint4 t3 = *(const uint4*)(gsrc + (3 * 512 + tid) * 8);
#pragma unroll
    for (int i = 0; i < 4; ++i) {
      int m = i * 512 + tid;
      int row = m >> 4, c = m & 15;
      uint4 v = (i == 0) ? t0 : (i == 1) ? t1 : (i == 2) ? t2 : t3;
      *(uint4*)(Als + row * 128 + ((c ^ (row & 15)) * 8)) = v;
    }
  }
  __syncthreads();

  const u16* WB0 = Wt0 + (h * 64) * 128;  // this wave's feature-half weights
  const u16* WB1 = Wt1 + (h * 64) * 128;

  f32x4 acc[2][2][4];  // [mat][rowset][j]
#pragma unroll
  for (int o = 0; o < 2; ++o)
#pragma unroll
    for (int i = 0; i < 2; ++i)
#pragma unroll
      for (int j = 0; j < 4; ++j) acc[o][i][j] = (f32x4){0.f, 0.f, 0.f, 0.f};

  int rl0 = g * 32 + lrow;   // local row for a0; a1 = rl0+16 (same &15)
#pragma unroll
  for (int kk = 0; kk < 128; kk += 32) {
    int c = ((kk >> 3) + q) ^ lrow;            // swizzled chunk for k=kk+q*8
    short8 a0 = *(const short8*)(Als + rl0 * 128 + c * 8);
    short8 a1 = *(const short8*)(Als + (rl0 + 16) * 128 + c * 8);
    int ko = kk + q * 8;
#pragma unroll
    for (int j = 0; j < 4; ++j) {
      short8 b0 = *(const short8*)(WB0 + (j * 16 + lrow) * 128 + ko);
      short8 b1 = *(const short8*)(WB1 + (j * 16 + lrow) * 128 + ko);
      acc[0][0][j] = __builtin_amdgcn_mfma_f32_16x16x32_bf16(b0, a0, acc[0][0][j], 0, 0, 0);
      acc[0][1][j] = __builtin_amdgcn_mfma_f32_16x16x32_bf16(b0, a1, acc[0][1][j], 0, 0, 0);
      acc[1][0][j] = __builtin_amdgcn_mfma_f32_16x16x32_bf16(b1, a0, acc[1][0][j], 0, 0, 0);
      acc[1][1][j] = __builtin_amdgcn_mfma_f32_16x16x32_bf16(b1, a1, acc[1][1][j], 0, 0, 0);
    }
  }

  // epilogue: lane owns row (tile0 + g*32 + i*16 + lrow);
  // features f = h*64 + j*16 + q*4 + r (4 consecutive per acc quad)
  if (ilv) {
#pragma unroll
    for (int i = 0; i < 2; ++i) {
      int grow = tile0 + g * 32 + i * 16 + lrow;
      if (grow < N) {
#pragma unroll
        for (int o = 0; o < 2; ++o) {
          // u16 offset within row: (f>>3)*16 + (o<<3) + (f&7)
          // f>>3 = h*8 + 2j + (q>>1); f&7 start = (q&1)*4
          u16* base = CKV + (size_t)grow * 256 + (o << 3) + ((q & 1) << 2) +
                      ((q >> 1) << 4) + h * 128;
#pragma unroll
          for (int j = 0; j < 4; ++j) {
            f32x4 v = acc[o][i][j];
            ushort4 pk;
            pk.x = f2bf(v[0]); pk.y = f2bf(v[1]); pk.z = f2bf(v[2]); pk.w = f2bf(v[3]);
            *(ushort4*)(base + j * 32) = pk;
          }
        }
      }
    }
  } else {
#pragma unroll
    for (int o = 0; o < 2; ++o) {
      u16* C = o ? CS : CQ;
#pragma unroll
      for (int i = 0; i < 2; ++i) {
        int grow = tile0 + g * 32 + i * 16 + lrow;
        if (grow < N) {
          u16* base = C + (size_t)grow * 128 + q * 4 + h * 64;
#pragma unroll
          for (int j = 0; j < 4; ++j) {
            f32x4 v = acc[o][i][j];
            ushort4 pk;
            pk.x = f2bf(v[0]); pk.y = f2bf(v[1]); pk.z = f2bf(v[2]); pk.w = f2bf(v[3]);
            *(ushort4*)(base + j * 16) = pk;
          }
        }
      }
    }
  }
}

// ---------- CSR build (both layers, rank-based fill) ----------
__global__ __launch_bounds__(256) void csr_count2(
    const int* __restrict__ dst0, const int* __restrict__ dst1,
    int* __restrict__ cnt, int* __restrict__ rank) {
  int t = blockIdx.x * 256 + threadIdx.x;
  if (t < E0N) {
    rank[t] = atomicAdd(&cnt[dst0[t]], 1);
  } else if (t < ET) {
    rank[t] = atomicAdd(&cnt[NE0 + dst1[t - E0N]], 1);
  }
}

__global__ __launch_bounds__(256) void scan1(const int* __restrict__ cnt,
                                             int* __restrict__ excl,
                                             int* __restrict__ blocksums, int N) {
  __shared__ int sh[256];
  int tid = threadIdx.x;
  int base = blockIdx.x * 1024 + tid * 4;
  int v0 = (base + 0 < N) ? cnt[base + 0] : 0;
  int v1 = (base + 1 < N) ? cnt[base + 1] : 0;
  int v2 = (base + 2 < N) ? cnt[base + 2] : 0;
  int v3 = (base + 3 < N) ? cnt[base + 3] : 0;
  int tsum = v0 + v1 + v2 + v3;
  sh[tid] = tsum;
  __syncthreads();
  for (int off = 1; off < 256; off <<= 1) {
    int t2 = (tid >= off) ? sh[tid - off] : 0;
    __syncthreads();
    sh[tid] += t2;
    __syncthreads();
  }
  int incl = sh[tid];
  if (tid == 255) blocksums[blockIdx.x] = incl;
  int run = incl - tsum;
  if (base + 0 < N) excl[base + 0] = run; run += v0;
  if (base + 1 < N) excl[base + 1] = run; run += v1;
  if (base + 2 < N) excl[base + 2] = run; run += v2;
  if (base + 3 < N) excl[base + 3] = run;
}

__global__ void scan2(int* __restrict__ blocksums, int nb) {
  __shared__ int sh[256];
  int tid = threadIdx.x;
  int v = (tid < nb) ? blocksums[tid] : 0;
  sh[tid] = v;
  __syncthreads();
  for (int off = 1; off < 256; off <<= 1) {
    int t2 = (tid >= off) ? sh[tid - off] : 0;
    __syncthreads();
    sh[tid] += t2;
    __syncthreads();
  }
  if (tid < nb) blocksums[tid] = sh[tid] - v;
}

__global__ __launch_bounds__(256) void scan3(int* __restrict__ offs,
                                             const int* __restrict__ blocksums, int N,
                                             int Etot) {
  int t = blockIdx.x * 256 + threadIdx.x;
  if (t < N) offs[t] += blocksums[t >> 10];
  if (t == 0) offs[N] = Etot;
}

__global__ __launch_bounds__(256) void csr_fill2(
    const int* __restrict__ dst0, const int* __restrict__ src0, const int* __restrict__ et0,
    const int* __restrict__ dst1, const int* __restrict__ src1, const int* __restrict__ et1,
    const int* __restrict__ offs, const int* __restrict__ rank,
    int* __restrict__ elist) {
  int t = blockIdx.x * 256 + threadIdx.x;
  if (t < E0N) {
    int p = offs[dst0[t]] + rank[t];
    elist[p] = (src0[t] << 2) | et0[t];
  } else if (t < ET) {
    int t2 = t - E0N;
    int p = offs[NE0 + dst1[t2]] + rank[t];
    elist[p] = (src1[t2] << 2) | et1[t2];
  }
}

// ---------- fused flash attention + skip combine ----------
// 4 dsts/wave, 16 lanes/dst, 8 consecutive dims/lane.
// KV table is interleaved: row = 16 groups of {K[8] | V[8]} bf16.
// Q pre-scaled by 0.25 (folded into Wq).
__device__ __forceinline__ float sel4(float s0, float s1, float s2, float s3, int ty) {
  float a = (ty & 1) ? s1 : s0;
  float b = (ty & 1) ? s3 : s2;
  return (ty & 2) ? b : a;
}

__global__ __launch_bounds__(256) void attn_fused(
    const int* __restrict__ elist, const int* __restrict__ offs,
    const u16* __restrict__ Q, const u16* __restrict__ KV,
    const float* __restrict__ ke, const float* __restrict__ ve,
    const u16* __restrict__ skipb, float* __restrict__ outp, int N) {
  int wave = (blockIdx.x * 256 + threadIdx.x) >> 6;
  int lane = threadIdx.x & 63;
  int which = lane >> 4;   // dst slot within wave
  int sub = lane & 15;     // 16 lanes per dst
  int d = wave * 4 + which;
  bool active = d < N;
  int dc = active ? d : 0;
  int dim0 = sub * 8;      // 8 consecutive dims per lane; head = sub>>1
  int sub16 = sub * 16;    // u16 offset of this lane's group within a KV row

  // Q: 8 dims as 4 packed bf16 pairs (already scaled by 1/sqrt(d))
  uint4 qp = *(const uint4*)(Q + (size_t)dc * D + dim0);
  f32x2 u0 = unpk(qp.x), u1 = unpk(qp.y), u2 = unpk(qp.z), u3 = unpk(qp.w);

  // per-type q . (We ek) : reduce over head (2 lanes)
  float qk0, qk1, qk2, qk3;
#pragma unroll
  for (int ty = 0; ty < 4; ++ty) {
    const float* kt = ke + ty * D + dim0;
    float4 ka = *(const float4*)kt;
    float4 kb = *(const float4*)(kt + 4);
    float p = u0.x * ka.x + u0.y * ka.y + u1.x * ka.z + u1.y * ka.w +
              u2.x * kb.x + u2.y * kb.y + u3.x * kb.z + u3.y * kb.w;
    p += __shfl_xor(p, 1, 64);
    if (ty == 0) qk0 = p; else if (ty == 1) qk1 = p; else if (ty == 2) qk2 = p; else qk3 = p;
  }

  int j0 = active ? offs[d] : 0;
  int j1 = active ? offs[d + 1] : 0;
  int j = j0;

  // prefetched current batch: edge codes + K-part rows
  int cp0, cp1, cp2, cp3;
  uint4 ck0, ck1, ck2, ck3;
  {
    int i0 = (j + 0 < j1) ? j + 0 : 0;
    int i1 = (j + 1 < j1) ? j + 1 : 0;
    int i2 = (j + 2 < j1) ? j + 2 : 0;
    int i3 = (j + 3 < j1) ? j + 3 : 0;
    cp0 = elist[i0]; cp1 = elist[i1]; cp2 = elist[i2]; cp3 = elist[i3];
    ck0 = *(const uint4*)(KV + (size_t)(cp0 >> 2) * 256 + sub16);
    ck1 = *(const uint4*)(KV + (size_t)(cp1 >> 2) * 256 + sub16);
    ck2 = *(const uint4*)(KV + (size_t)(cp2 >> 2) * 256 + sub16);
    ck3 = *(const uint4*)(KV + (size_t)(cp3 >> 2) * 256 + sub16);
  }

  float m = -INFINITY, s = 0.f;
  f32x2 acc01 = {0.f, 0.f}, acc23 = {0.f, 0.f}, acc45 = {0.f, 0.f}, acc67 = {0.f, 0.f};

  while (__any(j < j1)) {
    int jn = j + 4;
    // prefetch next batch (K-part only; clamped)
    int i0 = (jn + 0 < j1) ? jn + 0 : 0;
    int i1 = (jn + 1 < j1) ? jn + 1 : 0;
    int i2 = (jn + 2 < j1) ? jn + 2 : 0;
    int i3 = (jn + 3 < j1) ? jn + 3 : 0;
    int np0 = elist[i0], np1 = elist[i1], np2 = elist[i2], np3 = elist[i3];
    uint4 nk0 = *(const uint4*)(KV + (size_t)(np0 >> 2) * 256 + sub16);
    uint4 nk1 = *(const uint4*)(KV + (size_t)(np1 >> 2) * 256 + sub16);
    uint4 nk2 = *(const uint4*)(KV + (size_t)(np2 >> 2) * 256 + sub16);
    uint4 nk3 = *(const uint4*)(KV + (size_t)(np3 >> 2) * 256 + sub16);

    int n = j1 - j;
    if (n > 0) {
      int t0 = cp0 & 3, t1 = cp1 & 3, t2 = cp2 & 3, t3 = cp3 & 3;
      // issue V-part + type-table loads early (addrs ready from prefetch)
      uint4 cv0 = *(const uint4*)(KV + (size_t)(cp0 >> 2) * 256 + sub16 + 8);
      uint4 cv1 = *(const uint4*)(KV + (size_t)(cp1 >> 2) * 256 + sub16 + 8);
      uint4 cv2 = *(const uint4*)(KV + (size_t)(cp2 >> 2) * 256 + sub16 + 8);
      uint4 cv3 = *(const uint4*)(KV + (size_t)(cp3 >> 2) * 256 + sub16 + 8);
      const float* vp0 = ve + t0 * D + dim0;
      const float* vp1 = ve + t1 * D + dim0;
      const float* vp2 = ve + t2 * D + dim0;
      const float* vp3 = ve + t3 * D + dim0;
      float4 va0 = *(const float4*)vp0, vb0 = *(const float4*)(vp0 + 4);
      float4 va1 = *(const float4*)vp1, vb1 = *(const float4*)(vp1 + 4);
      float4 va2 = *(const float4*)vp2, vb2 = *(const float4*)(vp2 + 4);
      float4 va3 = *(const float4*)vp3, vb3 = *(const float4*)(vp3 + 4);

      // q . k over lane's 8 dims (bf16 dot2), then head-reduce over 2 lanes
      float p0 = dot2bf(qp.x, ck0.x, dot2bf(qp.y, ck0.y, dot2bf(qp.z, ck0.z, dot2bf(qp.w, ck0.w, 0.f))));
      float p1 = dot2bf(qp.x, ck1.x, dot2bf(qp.y, ck1.y, dot2bf(qp.z, ck1.z, dot2bf(qp.w, ck1.w, 0.f))));
      float p2 = dot2bf(qp.x, ck2.x, dot2bf(qp.y, ck2.y, dot2bf(qp.z, ck2.z, dot2bf(qp.w, ck2.w, 0.f))));
      float p3 = dot2bf(qp.x, ck3.x, dot2bf(qp.y, ck3.y, dot2bf(qp.z, ck3.z, dot2bf(qp.w, ck3.w, 0.f))));
      p0 += __shfl_xor(p0, 1, 64);
      p1 += __shfl_xor(p1, 1, 64);
      p2 += __shfl_xor(p2, 1, 64);
      p3 += __shfl_xor(p3, 1, 64);

      float l0 = p0 + sel4(qk0, qk1, qk2, qk3, t0);
      float l1 = p1 + sel4(qk0, qk1, qk2, qk3, t1);
      float l2 = p2 + sel4(qk0, qk1, qk2, qk3, t2);
      float l3 = p3 + sel4(qk0, qk1, qk2, qk3, t3);
      l0 = l0 >= 0.f ? l0 : 0.2f * l0;
      l1 = l1 >= 0.f ? l1 : 0.2f * l1;
      l2 = l2 >= 0.f ? l2 : 0.2f * l2;
      l3 = l3 >= 0.f ? l3 : 0.2f * l3;
      if (n < 2) l1 = -INFINITY;
      if (n < 3) l2 = -INFINITY;
      if (n < 4) l3 = -INFINITY;
      float mb = fmaxf(fmaxf(l0, l1), fmaxf(l2, l3));
      float mn = fmaxf(m, mb);
      float f = __expf(m - mn);
      float a0 = __expf(l0 - mn);
      float a1 = __expf(l1 - mn);
      float a2 = __expf(l2 - mn);
      float a3 = __expf(l3 - mn);
      s = s * f + ((a0 + a1) + (a2 + a3));
      f32x2 ff = {f, f};
      acc01 *= ff; acc23 *= ff; acc45 *= ff; acc67 *= ff;
      f32x2 aa0 = {a0, a0}, aa1 = {a1, a1}, aa2 = {a2, a2}, aa3 = {a3, a3};
      acc01 = fma2(aa0, unpk(cv0.x) + (f32x2){va0.x, va0.y}, acc01);
      acc23 = fma2(aa0, unpk(cv0.y) + (f32x2){va0.z, va0.w}, acc23);
      acc45 = fma2(aa0, unpk(cv0.z) + (f32x2){vb0.x, vb0.y}, acc45);
      acc67 = fma2(aa0, unpk(cv0.w) + (f32x2){vb0.z, vb0.w}, acc67);
      acc01 = fma2(aa1, unpk(cv1.x) + (f32x2){va1.x, va1.y}, acc01);
      acc23 = fma2(aa1, unpk(cv1.y) + (f32x2){va1.z, va1.w}, acc23);
      acc45 = fma2(aa1, unpk(cv1.z) + (f32x2){vb1.x, vb1.y}, acc45);
      acc67 = fma2(aa1, unpk(cv1.w) + (f32x2){vb1.z, vb1.w}, acc67);
      acc01 = fma2(aa2, unpk(cv2.x) + (f32x2){va2.x, va2.y}, acc01);
      acc23 = fma2(aa2, unpk(cv2.y) + (f32x2){va2.z, va2.w}, acc23);
      acc45 = fma2(aa2, unpk(cv2.z) + (f32x2){vb2.x, vb2.y}, acc45);
      acc67 = fma2(aa2, unpk(cv2.w) + (f32x2){vb2.z, vb2.w}, acc67);
      acc01 = fma2(aa3, unpk(cv3.x) + (f32x2){va3.x, va3.y}, acc01);
      acc23 = fma2(aa3, unpk(cv3.y) + (f32x2){va3.z, va3.w}, acc23);
      acc45 = fma2(aa3, unpk(cv3.z) + (f32x2){vb3.x, vb3.y}, acc45);
      acc67 = fma2(aa3, unpk(cv3.w) + (f32x2){vb3.z, vb3.w}, acc67);
      m = mn;
    }
    cp0 = np0; cp1 = np1; cp2 = np2; cp3 = np3;
    ck0 = nk0; ck1 = nk1; ck2 = nk2; ck3 = nk3;
    j = jn;
  }
  if (active) {
    float inv = 1.f / (s + 1e-16f);
    float hf = 0.5f * inv;
    uint4 sk = *(const uint4*)(skipb + (size_t)d * D + dim0);
    f32x2 s0 = unpk(sk.x), s1 = unpk(sk.y), s2 = unpk(sk.z), s3 = unpk(sk.w);
    float* op = outp + (size_t)d * D + dim0;
    float4 o0, o1;
    o0.x = 0.5f * s0.x + hf * acc01.x;
    o0.y = 0.5f * s0.y + hf * acc01.y;
    o0.z = 0.5f * s1.x + hf * acc23.x;
    o0.w = 0.5f * s1.y + hf * acc23.y;
    o1.x = 0.5f * s2.x + hf * acc45.x;
    o1.y = 0.5f * s2.y + hf * acc45.y;
    o1.z = 0.5f * s3.x + hf * acc67.x;
    o1.w = 0.5f * s3.y + hf * acc67.y;
    *(float4*)op = o0;
    *(float4*)(op + 4) = o1;
  }
}

// ---------- batch norm ----------
__global__ __launch_bounds__(256) void bn_reduce(const float* __restrict__ h,
                                                 float* __restrict__ sums, int N) {
  int c = threadIdx.x & 127;
  int rofs = threadIdx.x >> 7;
  float s0 = 0.f, s1 = 0.f;
  for (int r = blockIdx.x * 2 + rofs; r < N; r += gridDim.x * 2) {
    float v = h[(size_t)r * 128 + c];
    s0 += v;
    s1 += v * v;
  }
  __shared__ float ls[256], lq[256];
  ls[threadIdx.x] = s0;
  lq[threadIdx.x] = s1;
  __syncthreads();
  if (threadIdx.x < 128) {
    atomicAdd(&sums[c], ls[threadIdx.x] + ls[threadIdx.x + 128]);
    atomicAdd(&sums[128 + c], lq[threadIdx.x] + lq[threadIdx.x + 128]);
  }
}

__global__ __launch_bounds__(256) void bn_apply(const float* __restrict__ h,
                                                u16* __restrict__ hbf,
                                                const float* __restrict__ sums,
                                                const float* __restrict__ gamma,
                                                const float* __restrict__ beta,
                                                float invN, int total) {
  __shared__ float sc[128], sh[128];
  int tid = threadIdx.x;
  if (tid < 128) {
    float mu = sums[tid] * invN;
    float var = sums[128 + tid] * invN - mu * mu;
    float inv = rsqrtf(var + 1e-5f);
    float s = gamma[tid] * inv;
    sc[tid] = s;
    sh[tid] = beta[tid] - mu * s;
  }
  __syncthreads();
  int i = blockIdx.x * 256 + tid;
  if (i < total) {
    int c = i & 127;
    hbf[i] = f2bf(h[i] * sc[c] + sh[c]);
  }
}

// ---------- launch ----------
extern "C" void kernel_launch(void* const* d_in, const int* in_sizes, int n_in,
                              void* d_out, int out_size, void* d_ws, size_t ws_size,
                              hipStream_t stream) {
  const float* x        = (const float*)d_in[0];
  const int*   ei0      = (const int*)d_in[1];
  const int*   et0      = (const int*)d_in[2];
  const int*   ei1      = (const int*)d_in[3];
  const int*   et1      = (const int*)d_in[4];
  const float* emb_type = (const float*)d_in[5];
  const float* emb_attr = (const float*)d_in[6];
  const float* v2e_Wq   = (const float*)d_in[7];
  const float* v2e_Wk   = (const float*)d_in[8];
  const float* v2e_Wv   = (const float*)d_in[9];
  const float* v2e_We   = (const float*)d_in[10];
  const float* v2e_Wsk  = (const float*)d_in[11];
  const float* e2_Wq    = (const float*)d_in[12];
  const float* e2_Wk    = (const float*)d_in[13];
  const float* e2_Wv    = (const float*)d_in[14];
  const float* e2_We    = (const float*)d_in[15];
  const float* e2_Wsk   = (const float*)d_in[16];
  const float* bn_gamma = (const float*)d_in[17];
  const float* bn_beta  = (const float*)d_in[18];
  float* out = (float*)d_out;

  // workspace layout
  char* wsb = (char*)d_ws;
  size_t off = 0;
  u16* xb  = (u16*)(wsb + off);  off += (size_t)NSRC * D * 2;
  u16* KVb = (u16*)(wsb + off);  off += (size_t)NSRC * D * 2 * 2;  // interleaved K|V
  u16* Qb  = (u16*)(wsb + off);  off += (size_t)NE0 * D * 2;
  u16* Sb  = (u16*)(wsb + off);  off += (size_t)NE0 * D * 2;
  float* hb = (float*)(wsb + off); off += (size_t)NE0 * D * 4;
  u16* hbf = (u16*)(wsb + off);  off += (size_t)NE0 * D * 2;
  u16* wtAll = (u16*)(wsb + off); off += 8 * 16384 * 2;
  int* elist = (int*)(wsb + off);  off += (size_t)ET * 4;
  int* rank  = (int*)(wsb + off);  off += (size_t)ET * 4;
  int* offs  = (int*)(wsb + off);  off += ((size_t)NT + 8) * 4;
  int* bsums = (int*)(wsb + off);  off += 1024;
  float* kv  = (float*)(wsb + off); off += 4 * 512 * 4;
  float* bnsums = (float*)(wsb + off); off += 256 * 4;  // sum[128] | sumsq[128]

  u16* wtK0 = wtAll + 0 * 16384;
  u16* wtV0 = wtAll + 1 * 16384;
  u16* wtQ0 = wtAll + 2 * 16384;
  u16* wtS0 = wtAll + 3 * 16384;
  u16* wtK1 = wtAll + 4 * 16384;
  u16* wtV1 = wtAll + 5 * 16384;
  u16* wtQ1 = wtAll + 6 * 16384;
  u16* wtS1 = wtAll + 7 * 16384;
  float* kep0 = kv;
  float* vep0 = kv + 512;
  float* kep1 = kv + 1024;
  float* vep1 = kv + 1536;

  const int* src0 = ei0;
  const int* dst0 = ei0 + E0N;
  const int* src1 = ei1;
  const int* dst1 = ei1 + E1N;

  // 1: mega-prep (cast + weights + embs + zeroing)
  prep_all<<<BC + 64 + 4 + BZ + 1, 256, 0, stream>>>(
      x, xb, v2e_Wk, v2e_Wv, v2e_Wq, v2e_Wsk, e2_Wk, e2_Wv, e2_Wq, e2_Wsk,
      wtAll, emb_type, emb_attr, v2e_We, e2_We, kv, offs, bnsums);

  // 2-6: CSR for both layers
  csr_count2<<<(ET + 255) / 256, 256, 0, stream>>>(dst0, dst1, offs, rank);
  {
    int nb = (NT + 1023) / 1024;
    scan1<<<nb, 256, 0, stream>>>(offs, offs, bsums, NT);
    scan2<<<1, 256, 0, stream>>>(bsums, nb);
    scan3<<<(NT + 255) / 256, 256, 0, stream>>>(offs, bsums, NT, ET);
  }
  csr_fill2<<<(ET + 255) / 256, 256, 0, stream>>>(dst0, src0, et0, dst1, src1, et1,
                                                  offs, rank, elist);

  // 7-10: layer 0
  {
    int nKV = (NSRC + 127) / 128, nQS = (NE0 + 127) / 128;
    gemm_quad<<<nKV + nQS, 512, 0, stream>>>(xb, wtK0, wtV0, KVb, NSRC, nKV,
                                             wtQ0, wtS0, Qb, Sb, NE0);
  }
  attn_fused<<<(NE0 + 15) / 16, 256, 0, stream>>>(elist, offs, Qb, KVb, kep0, vep0,
                                                  Sb, hb, NE0);
  bn_reduce<<<256, 256, 0, stream>>>(hb, bnsums, NE0);
  bn_apply<<<(NE0 * D + 255) / 256, 256, 0, stream>>>(hb, hbf, bnsums, bn_gamma, bn_beta,
                                                      1.0f / (float)NE0, NE0 * D);

  // 11-12: layer 1
  {
    int nKV = (NE0 + 127) / 128, nQS = (NE1 + 127) / 128;
    gemm_quad<<<nKV + nQS, 512, 0, stream>>>(hbf, wtK1, wtV1, KVb, NE0, nKV,
                                             wtQ1, wtS1, Qb, Sb, NE1);
  }
  attn_fused<<<(NE1 + 15) / 16, 256, 0, stream>>>(elist, offs + NE0, Qb, KVb, kep1, vep1,
                                                  Sb, out, NE1);
}

// Round 5
// 650.315 us; speedup vs baseline: 1.2120x; 1.1256x over previous
//
#include <hip/hip_runtime.h>
#include <cstdint>
#include <cstddef>

#define D 128
#define H 8
#define NSRC 200000
#define NE0  100000
#define NE1  50000
#define E0N  1000000
#define E1N  500000
#define NT   (NE0 + NE1)
#define ET   (E0N + E1N)

typedef unsigned short u16;
typedef __attribute__((ext_vector_type(8))) short short8;
typedef __attribute__((ext_vector_type(4))) float f32x4;
typedef __attribute__((ext_vector_type(2))) float f32x2;

// ---------- bf16 helpers ----------
__device__ __forceinline__ u16 f2bf(float f) {
  unsigned u = __float_as_uint(f);
  unsigned r = (u + 0x7fffu + ((u >> 16) & 1u)) >> 16;  // RNE
  return (u16)r;
}
__device__ __forceinline__ float bf2f(u16 u) {
  return __uint_as_float(((unsigned)u) << 16);
}
// unpack 2 packed bf16 (low = even dim) -> f32x2
__device__ __forceinline__ f32x2 unpk(unsigned u) {
  f32x2 r;
  r.x = __uint_as_float(u << 16);
  r.y = __uint_as_float(u & 0xffff0000u);
  return r;
}
// bf16 pair dot with f32 accumulate: d = a.lo*b.lo + a.hi*b.hi + c
__device__ __forceinline__ float dot2bf(unsigned a, unsigned b, float c) {
  float d;
  asm("v_dot2_f32_bf16 %0, %1, %2, %3" : "=v"(d) : "v"(a), "v"(b), "v"(c));
  return d;
}
__device__ __forceinline__ f32x2 fma2(f32x2 a, f32x2 b, f32x2 c) {
  return __builtin_elementwise_fma(a, b, c);
}

// ---------- mega-prep: x cast + weight transpose + emb GEMMs + zero-fill ----------
// block roles: [0,BC) cast | [BC,BC+64) weights | +4 embs | +BZ zero offs | +1 zero bn
#define BC 25000            // (NSRC*D/4)/256
#define BZ 147              // ceil((NT+1)/1024)
static_assert((size_t)BZ * 1024 >= NT + 1, "offs zero-fill must cover NT+1 entries");
__global__ __launch_bounds__(256) void prep_all(
    const float* __restrict__ x, u16* __restrict__ xb,
    const float* w0, const float* w1, const float* w2, const float* w3,
    const float* w4, const float* w5, const float* w6, const float* w7,
    u16* __restrict__ wt,
    const float* __restrict__ embA, const float* __restrict__ embB,
    const float* __restrict__ We0, const float* __restrict__ We1,
    float* __restrict__ kv,
    int* __restrict__ offs, float* __restrict__ bnsums) {
  int b = blockIdx.x;
  if (b < BC) {
    int i = b * 256 + threadIdx.x;
    float4 a = ((const float4*)x)[i];
    ushort4 o;
    o.x = f2bf(a.x); o.y = f2bf(a.y); o.z = f2bf(a.z); o.w = f2bf(a.w);
    ((ushort4*)xb)[i] = o;
  } else if (b < BC + 64) {
    int bb = b - BC;
    const float* wsrc[8] = {w0, w1, w2, w3, w4, w5, w6, w7};
    int mat = bb >> 3;
    int blk = bb & 7;
    const float* W = wsrc[mat];
    // fold 1/sqrt(d)=0.25 into Wq (mats 2 and 6) so Q comes out pre-scaled
    float sc = ((mat & 3) == 2) ? 0.25f : 1.0f;
    u16* out = wt + mat * 16384;
    for (int i = blk * 2048 + threadIdx.x; i < (blk + 1) * 2048; i += 256) {
      int n = i >> 7, k = i & 127;
      out[i] = f2bf(W[k * 128 + n] * sc);
    }
  } else if (b < BC + 68) {
    int bb = b - BC - 64;
    int mat = bb >> 1;
    int t = (bb & 1) * 256 + threadIdx.x;
    const float* We = mat ? We1 : We0;
    float* keOut = kv + mat * 1024;
    float* veOut = keOut + 512;
    int r = t >> 7, c = t & 127;
    float s0 = 0.f, s1 = 0.f;
    for (int k = 0; k < 128; ++k) {
      float w = We[k * 128 + c];
      s0 += embA[r * 128 + k] * w;
      s1 += embB[r * 128 + k] * w;
    }
    keOut[t] = s0;
    veOut[t] = s1;
  } else if (b < BC + 68 + BZ) {
    int base = (b - BC - 68) * 1024 + threadIdx.x * 4;
#pragma unroll
    for (int i = 0; i < 4; ++i)
      if (base + i < NT + 1) offs[base + i] = 0;
  } else {
    bnsums[threadIdx.x] = 0.f;  // 256 floats = bnsum|bnsq
  }
}

// ---------- quad-output MFMA GEMM, weights-in-LDS (R5) ----------
// R4 post-mortem: A-in-LDS left dur flat. Remaining global chain = per-kk
// weight loads: 8 x 16B scattered (16 rows x 256B stride = 16 sectors/instr)
// and 64 KB weights thrash the 32 KB L1 -> every kk serializes on an L2
// round-trip. Fix: invert the staging. Weights (64 KB, identical for every
// block) -> LDS once per block, chunk-XOR swizzled; A-fragments (8 x 16B =
// the wave's whole K-extent) -> registers, issued AFTER the weight loads so
// FIFO vmcnt lets staging complete (vmcnt(8)) while A stays in flight; A's
// HBM latency hides under staging+barrier. K-loop = ds_read_b128 + MFMA only.
// mfma(b, a, acc): lane owns one data row, acc regs = 4 consecutive features
// -> packed 8B stores, full line coverage.
__global__ __launch_bounds__(512, 4) void gemm_quad(
    const u16* __restrict__ A,
    const u16* __restrict__ WtK, const u16* __restrict__ WtV,
    u16* __restrict__ CKV, int NA, int nKV,
    const u16* __restrict__ WtQ, const u16* __restrict__ WtS,
    u16* __restrict__ CQ, u16* __restrict__ CS, int NB) {
  int bb = blockIdx.x;
  const u16 *Wt0, *Wt1;
  int N, tile0;
  bool ilv = (bb < nKV);
  if (ilv) {
    Wt0 = WtK; Wt1 = WtV; N = NA; tile0 = bb * 128;
  } else {
    Wt0 = WtQ; Wt1 = WtS; N = NB; tile0 = (bb - nKV) * 128;
  }
  int tid = threadIdx.x;
  int w = tid >> 6, lane = tid & 63;
  int g = w >> 1;          // row group: rows [g*32, g*32+32)
  int h = w & 1;           // feature half: features [h*64, h*64+64)
  int lrow = lane & 15, q = lane >> 4;

  __shared__ u16 Wls[2 * 128 * 128];  // 64 KB: both mats, chunk-XOR swizzled

  // 1) issue weight-staging loads FIRST (same 64 KB for all blocks -> L2-hot)
  uint4 wv[8];
#pragma unroll
  for (int i = 0; i < 8; ++i) {
    int m = i * 512 + tid;                       // 4096 x 16B chunks
    const u16* Wsrc = (m >> 11) ? Wt1 : Wt0;
    wv[i] = *(const uint4*)(Wsrc + (size_t)(m & 2047) * 8);
  }

  // 2) issue A-fragment loads (whole K-extent to regs); newer in VMEM FIFO,
  //    so staging's waitcnt leaves them in flight.
  int ra = tile0 + g * 32 + lrow;
  int rb = ra + 16;
  bool oka = ra < N, okb = rb < N;
  const u16* pa = A + (size_t)(oka ? ra : 0) * 128 + q * 8;
  const u16* pb = A + (size_t)(okb ? rb : 0) * 128 + q * 8;
  short8 av[4], bv[4];
#pragma unroll
  for (int kk = 0; kk < 4; ++kk) {
    av[kk] = *(const short8*)(pa + kk * 32);
    bv[kk] = *(const short8*)(pb + kk * 32);
  }

  // 3) LDS write (chunk-XOR swizzle: LDS(row,c) = W(row, c ^ (row&15)))
#pragma unroll
  for (int i = 0; i < 8; ++i) {
    int m = i * 512 + tid;
    int row = (m & 2047) >> 4, c = m & 15;
    *(uint4*)(Wls + (m >> 11) * 16384 + row * 128 + (c ^ (row & 15)) * 8) = wv[i];
  }
  __syncthreads();

  const u16* W0 = Wls + (h * 64) * 128;          // mat0, this wave's half
  const u16* W1 = Wls + 16384 + (h * 64) * 128;  // mat1, this wave's half

  f32x4 acc[2][2][4];  // [mat][rowset][j]
#pragma unroll
  for (int o = 0; o < 2; ++o)
#pragma unroll
    for (int i = 0; i < 2; ++i)
#pragma unroll
      for (int j = 0; j < 4; ++j) acc[o][i][j] = (f32x4){0.f, 0.f, 0.f, 0.f};

  const short8 zero8 = {0, 0, 0, 0, 0, 0, 0, 0};
#pragma unroll
  for (int kk = 0; kk < 4; ++kk) {
    short8 a0 = oka ? av[kk] : zero8;
    short8 a1 = okb ? bv[kk] : zero8;
    int cs = ((kk * 4 + q) ^ lrow) * 8;          // swizzled chunk offset
#pragma unroll
    for (int j = 0; j < 4; ++j) {
      int fr = j * 16 + lrow;                    // (global row &15) == lrow
      short8 b0 = *(const short8*)(W0 + fr * 128 + cs);
      short8 b1 = *(const short8*)(W1 + fr * 128 + cs);
      acc[0][0][j] = __builtin_amdgcn_mfma_f32_16x16x32_bf16(b0, a0, acc[0][0][j], 0, 0, 0);
      acc[0][1][j] = __builtin_amdgcn_mfma_f32_16x16x32_bf16(b0, a1, acc[0][1][j], 0, 0, 0);
      acc[1][0][j] = __builtin_amdgcn_mfma_f32_16x16x32_bf16(b1, a0, acc[1][0][j], 0, 0, 0);
      acc[1][1][j] = __builtin_amdgcn_mfma_f32_16x16x32_bf16(b1, a1, acc[1][1][j], 0, 0, 0);
    }
  }

  // epilogue: lane owns row (tile0 + g*32 + i*16 + lrow);
  // features f = h*64 + j*16 + q*4 + r (4 consecutive per acc quad)
  if (ilv) {
#pragma unroll
    for (int i = 0; i < 2; ++i) {
      int grow = tile0 + g * 32 + i * 16 + lrow;
      if (grow < N) {
#pragma unroll
        for (int o = 0; o < 2; ++o) {
          // u16 offset within row: (f>>3)*16 + (o<<3) + (f&7)
          // f>>3 = h*8 + 2j + (q>>1); f&7 start = (q&1)*4
          u16* base = CKV + (size_t)grow * 256 + (o << 3) + ((q & 1) << 2) +
                      ((q >> 1) << 4) + h * 128;
#pragma unroll
          for (int j = 0; j < 4; ++j) {
            f32x4 v = acc[o][i][j];
            ushort4 pk;
            pk.x = f2bf(v[0]); pk.y = f2bf(v[1]); pk.z = f2bf(v[2]); pk.w = f2bf(v[3]);
            *(ushort4*)(base + j * 32) = pk;
          }
        }
      }
    }
  } else {
#pragma unroll
    for (int o = 0; o < 2; ++o) {
      u16* C = o ? CS : CQ;
#pragma unroll
      for (int i = 0; i < 2; ++i) {
        int grow = tile0 + g * 32 + i * 16 + lrow;
        if (grow < N) {
          u16* base = C + (size_t)grow * 128 + q * 4 + h * 64;
#pragma unroll
          for (int j = 0; j < 4; ++j) {
            f32x4 v = acc[o][i][j];
            ushort4 pk;
            pk.x = f2bf(v[0]); pk.y = f2bf(v[1]); pk.z = f2bf(v[2]); pk.w = f2bf(v[3]);
            *(ushort4*)(base + j * 16) = pk;
          }
        }
      }
    }
  }
}

// ---------- CSR build (both layers, rank-based fill) ----------
__global__ __launch_bounds__(256) void csr_count2(
    const int* __restrict__ dst0, const int* __restrict__ dst1,
    int* __restrict__ cnt, int* __restrict__ rank) {
  int t = blockIdx.x * 256 + threadIdx.x;
  if (t < E0N) {
    rank[t] = atomicAdd(&cnt[dst0[t]], 1);
  } else if (t < ET) {
    rank[t] = atomicAdd(&cnt[NE0 + dst1[t - E0N]], 1);
  }
}

__global__ __launch_bounds__(256) void scan1(const int* __restrict__ cnt,
                                             int* __restrict__ excl,
                                             int* __restrict__ blocksums, int N) {
  __shared__ int sh[256];
  int tid = threadIdx.x;
  int base = blockIdx.x * 1024 + tid * 4;
  int v0 = (base + 0 < N) ? cnt[base + 0] : 0;
  int v1 = (base + 1 < N) ? cnt[base + 1] : 0;
  int v2 = (base + 2 < N) ? cnt[base + 2] : 0;
  int v3 = (base + 3 < N) ? cnt[base + 3] : 0;
  int tsum = v0 + v1 + v2 + v3;
  sh[tid] = tsum;
  __syncthreads();
  for (int off = 1; off < 256; off <<= 1) {
    int t2 = (tid >= off) ? sh[tid - off] : 0;
    __syncthreads();
    sh[tid] += t2;
    __syncthreads();
  }
  int incl = sh[tid];
  if (tid == 255) blocksums[blockIdx.x] = incl;
  int run = incl - tsum;
  if (base + 0 < N) excl[base + 0] = run; run += v0;
  if (base + 1 < N) excl[base + 1] = run; run += v1;
  if (base + 2 < N) excl[base + 2] = run; run += v2;
  if (base + 3 < N) excl[base + 3] = run;
}

__global__ void scan2(int* __restrict__ blocksums, int nb) {
  __shared__ int sh[256];
  int tid = threadIdx.x;
  int v = (tid < nb) ? blocksums[tid] : 0;
  sh[tid] = v;
  __syncthreads();
  for (int off = 1; off < 256; off <<= 1) {
    int t2 = (tid >= off) ? sh[tid - off] : 0;
    __syncthreads();
    sh[tid] += t2;
    __syncthreads();
  }
  if (tid < nb) blocksums[tid] = sh[tid] - v;
}

__global__ __launch_bounds__(256) void scan3(int* __restrict__ offs,
                                             const int* __restrict__ blocksums, int N,
                                             int Etot) {
  int t = blockIdx.x * 256 + threadIdx.x;
  if (t < N) offs[t] += blocksums[t >> 10];
  if (t == 0) offs[N] = Etot;
}

__global__ __launch_bounds__(256) void csr_fill2(
    const int* __restrict__ dst0, const int* __restrict__ src0, const int* __restrict__ et0,
    const int* __restrict__ dst1, const int* __restrict__ src1, const int* __restrict__ et1,
    const int* __restrict__ offs, const int* __restrict__ rank,
    int* __restrict__ elist) {
  int t = blockIdx.x * 256 + threadIdx.x;
  if (t < E0N) {
    int p = offs[dst0[t]] + rank[t];
    elist[p] = (src0[t] << 2) | et0[t];
  } else if (t < ET) {
    int t2 = t - E0N;
    int p = offs[NE0 + dst1[t2]] + rank[t];
    elist[p] = (src1[t2] << 2) | et1[t2];
  }
}

// ---------- fused flash attention + skip combine ----------
// 4 dsts/wave, 16 lanes/dst, 8 consecutive dims/lane.
// KV table is interleaved: row = 16 groups of {K[8] | V[8]} bf16.
// Q pre-scaled by 0.25 (folded into Wq).
__device__ __forceinline__ float sel4(float s0, float s1, float s2, float s3, int ty) {
  float a = (ty & 1) ? s1 : s0;
  float b = (ty & 1) ? s3 : s2;
  return (ty & 2) ? b : a;
}

__global__ __launch_bounds__(256) void attn_fused(
    const int* __restrict__ elist, const int* __restrict__ offs,
    const u16* __restrict__ Q, const u16* __restrict__ KV,
    const float* __restrict__ ke, const float* __restrict__ ve,
    const u16* __restrict__ skipb, float* __restrict__ outp, int N) {
  int wave = (blockIdx.x * 256 + threadIdx.x) >> 6;
  int lane = threadIdx.x & 63;
  int which = lane >> 4;   // dst slot within wave
  int sub = lane & 15;     // 16 lanes per dst
  int d = wave * 4 + which;
  bool active = d < N;
  int dc = active ? d : 0;
  int dim0 = sub * 8;      // 8 consecutive dims per lane; head = sub>>1
  int sub16 = sub * 16;    // u16 offset of this lane's group within a KV row

  // Q: 8 dims as 4 packed bf16 pairs (already scaled by 1/sqrt(d))
  uint4 qp = *(const uint4*)(Q + (size_t)dc * D + dim0);
  f32x2 u0 = unpk(qp.x), u1 = unpk(qp.y), u2 = unpk(qp.z), u3 = unpk(qp.w);

  // per-type q . (We ek) : reduce over head (2 lanes)
  float qk0, qk1, qk2, qk3;
#pragma unroll
  for (int ty = 0; ty < 4; ++ty) {
    const float* kt = ke + ty * D + dim0;
    float4 ka = *(const float4*)kt;
    float4 kb = *(const float4*)(kt + 4);
    float p = u0.x * ka.x + u0.y * ka.y + u1.x * ka.z + u1.y * ka.w +
              u2.x * kb.x + u2.y * kb.y + u3.x * kb.z + u3.y * kb.w;
    p += __shfl_xor(p, 1, 64);
    if (ty == 0) qk0 = p; else if (ty == 1) qk1 = p; else if (ty == 2) qk2 = p; else qk3 = p;
  }

  int j0 = active ? offs[d] : 0;
  int j1 = active ? offs[d + 1] : 0;
  int j = j0;

  // prefetched current batch: edge codes + K-part rows
  int cp0, cp1, cp2, cp3;
  uint4 ck0, ck1, ck2, ck3;
  {
    int i0 = (j + 0 < j1) ? j + 0 : 0;
    int i1 = (j + 1 < j1) ? j + 1 : 0;
    int i2 = (j + 2 < j1) ? j + 2 : 0;
    int i3 = (j + 3 < j1) ? j + 3 : 0;
    cp0 = elist[i0]; cp1 = elist[i1]; cp2 = elist[i2]; cp3 = elist[i3];
    ck0 = *(const uint4*)(KV + (size_t)(cp0 >> 2) * 256 + sub16);
    ck1 = *(const uint4*)(KV + (size_t)(cp1 >> 2) * 256 + sub16);
    ck2 = *(const uint4*)(KV + (size_t)(cp2 >> 2) * 256 + sub16);
    ck3 = *(const uint4*)(KV + (size_t)(cp3 >> 2) * 256 + sub16);
  }

  float m = -INFINITY, s = 0.f;
  f32x2 acc01 = {0.f, 0.f}, acc23 = {0.f, 0.f}, acc45 = {0.f, 0.f}, acc67 = {0.f, 0.f};

  while (__any(j < j1)) {
    int jn = j + 4;
    // prefetch next batch (K-part only; clamped)
    int i0 = (jn + 0 < j1) ? jn + 0 : 0;
    int i1 = (jn + 1 < j1) ? jn + 1 : 0;
    int i2 = (jn + 2 < j1) ? jn + 2 : 0;
    int i3 = (jn + 3 < j1) ? jn + 3 : 0;
    int np0 = elist[i0], np1 = elist[i1], np2 = elist[i2], np3 = elist[i3];
    uint4 nk0 = *(const uint4*)(KV + (size_t)(np0 >> 2) * 256 + sub16);
    uint4 nk1 = *(const uint4*)(KV + (size_t)(np1 >> 2) * 256 + sub16);
    uint4 nk2 = *(const uint4*)(KV + (size_t)(np2 >> 2) * 256 + sub16);
    uint4 nk3 = *(const uint4*)(KV + (size_t)(np3 >> 2) * 256 + sub16);

    int n = j1 - j;
    if (n > 0) {
      int t0 = cp0 & 3, t1 = cp1 & 3, t2 = cp2 & 3, t3 = cp3 & 3;
      // issue V-part + type-table loads early (addrs ready from prefetch)
      uint4 cv0 = *(const uint4*)(KV + (size_t)(cp0 >> 2) * 256 + sub16 + 8);
      uint4 cv1 = *(const uint4*)(KV + (size_t)(cp1 >> 2) * 256 + sub16 + 8);
      uint4 cv2 = *(const uint4*)(KV + (size_t)(cp2 >> 2) * 256 + sub16 + 8);
      uint4 cv3 = *(const uint4*)(KV + (size_t)(cp3 >> 2) * 256 + sub16 + 8);
      const float* vp0 = ve + t0 * D + dim0;
      const float* vp1 = ve + t1 * D + dim0;
      const float* vp2 = ve + t2 * D + dim0;
      const float* vp3 = ve + t3 * D + dim0;
      float4 va0 = *(const float4*)vp0, vb0 = *(const float4*)(vp0 + 4);
      float4 va1 = *(const float4*)vp1, vb1 = *(const float4*)(vp1 + 4);
      float4 va2 = *(const float4*)vp2, vb2 = *(const float4*)(vp2 + 4);
      float4 va3 = *(const float4*)vp3, vb3 = *(const float4*)(vp3 + 4);

      // q . k over lane's 8 dims (bf16 dot2), then head-reduce over 2 lanes
      float p0 = dot2bf(qp.x, ck0.x, dot2bf(qp.y, ck0.y, dot2bf(qp.z, ck0.z, dot2bf(qp.w, ck0.w, 0.f))));
      float p1 = dot2bf(qp.x, ck1.x, dot2bf(qp.y, ck1.y, dot2bf(qp.z, ck1.z, dot2bf(qp.w, ck1.w, 0.f))));
      float p2 = dot2bf(qp.x, ck2.x, dot2bf(qp.y, ck2.y, dot2bf(qp.z, ck2.z, dot2bf(qp.w, ck2.w, 0.f))));
      float p3 = dot2bf(qp.x, ck3.x, dot2bf(qp.y, ck3.y, dot2bf(qp.z, ck3.z, dot2bf(qp.w, ck3.w, 0.f))));
      p0 += __shfl_xor(p0, 1, 64);
      p1 += __shfl_xor(p1, 1, 64);
      p2 += __shfl_xor(p2, 1, 64);
      p3 += __shfl_xor(p3, 1, 64);

      float l0 = p0 + sel4(qk0, qk1, qk2, qk3, t0);
      float l1 = p1 + sel4(qk0, qk1, qk2, qk3, t1);
      float l2 = p2 + sel4(qk0, qk1, qk2, qk3, t2);
      float l3 = p3 + sel4(qk0, qk1, qk2, qk3, t3);
      l0 = l0 >= 0.f ? l0 : 0.2f * l0;
      l1 = l1 >= 0.f ? l1 : 0.2f * l1;
      l2 = l2 >= 0.f ? l2 : 0.2f * l2;
      l3 = l3 >= 0.f ? l3 : 0.2f * l3;
      if (n < 2) l1 = -INFINITY;
      if (n < 3) l2 = -INFINITY;
      if (n < 4) l3 = -INFINITY;
      float mb = fmaxf(fmaxf(l0, l1), fmaxf(l2, l3));
      float mn = fmaxf(m, mb);
      float f = __expf(m - mn);
      float a0 = __expf(l0 - mn);
      float a1 = __expf(l1 - mn);
      float a2 = __expf(l2 - mn);
      float a3 = __expf(l3 - mn);
      s = s * f + ((a0 + a1) + (a2 + a3));
      f32x2 ff = {f, f};
      acc01 *= ff; acc23 *= ff; acc45 *= ff; acc67 *= ff;
      f32x2 aa0 = {a0, a0}, aa1 = {a1, a1}, aa2 = {a2, a2}, aa3 = {a3, a3};
      acc01 = fma2(aa0, unpk(cv0.x) + (f32x2){va0.x, va0.y}, acc01);
      acc23 = fma2(aa0, unpk(cv0.y) + (f32x2){va0.z, va0.w}, acc23);
      acc45 = fma2(aa0, unpk(cv0.z) + (f32x2){vb0.x, vb0.y}, acc45);
      acc67 = fma2(aa0, unpk(cv0.w) + (f32x2){vb0.z, vb0.w}, acc67);
      acc01 = fma2(aa1, unpk(cv1.x) + (f32x2){va1.x, va1.y}, acc01);
      acc23 = fma2(aa1, unpk(cv1.y) + (f32x2){va1.z, va1.w}, acc23);
      acc45 = fma2(aa1, unpk(cv1.z) + (f32x2){vb1.x, vb1.y}, acc45);
      acc67 = fma2(aa1, unpk(cv1.w) + (f32x2){vb1.z, vb1.w}, acc67);
      acc01 = fma2(aa2, unpk(cv2.x) + (f32x2){va2.x, va2.y}, acc01);
      acc23 = fma2(aa2, unpk(cv2.y) + (f32x2){va2.z, va2.w}, acc23);
      acc45 = fma2(aa2, unpk(cv2.z) + (f32x2){vb2.x, vb2.y}, acc45);
      acc67 = fma2(aa2, unpk(cv2.w) + (f32x2){vb2.z, vb2.w}, acc67);
      acc01 = fma2(aa3, unpk(cv3.x) + (f32x2){va3.x, va3.y}, acc01);
      acc23 = fma2(aa3, unpk(cv3.y) + (f32x2){va3.z, va3.w}, acc23);
      acc45 = fma2(aa3, unpk(cv3.z) + (f32x2){vb3.x, vb3.y}, acc45);
      acc67 = fma2(aa3, unpk(cv3.w) + (f32x2){vb3.z, vb3.w}, acc67);
      m = mn;
    }
    cp0 = np0; cp1 = np1; cp2 = np2; cp3 = np3;
    ck0 = nk0; ck1 = nk1; ck2 = nk2; ck3 = nk3;
    j = jn;
  }
  if (active) {
    float inv = 1.f / (s + 1e-16f);
    float hf = 0.5f * inv;
    uint4 sk = *(const uint4*)(skipb + (size_t)d * D + dim0);
    f32x2 s0 = unpk(sk.x), s1 = unpk(sk.y), s2 = unpk(sk.z), s3 = unpk(sk.w);
    float* op = outp + (size_t)d * D + dim0;
    float4 o0, o1;
    o0.x = 0.5f * s0.x + hf * acc01.x;
    o0.y = 0.5f * s0.y + hf * acc01.y;
    o0.z = 0.5f * s1.x + hf * acc23.x;
    o0.w = 0.5f * s1.y + hf * acc23.y;
    o1.x = 0.5f * s2.x + hf * acc45.x;
    o1.y = 0.5f * s2.y + hf * acc45.y;
    o1.z = 0.5f * s3.x + hf * acc67.x;
    o1.w = 0.5f * s3.y + hf * acc67.y;
    *(float4*)op = o0;
    *(float4*)(op + 4) = o1;
  }
}

// ---------- batch norm ----------
__global__ __launch_bounds__(256) void bn_reduce(const float* __restrict__ h,
                                                 float* __restrict__ sums, int N) {
  int c = threadIdx.x & 127;
  int rofs = threadIdx.x >> 7;
  float s0 = 0.f, s1 = 0.f;
  for (int r = blockIdx.x * 2 + rofs; r < N; r += gridDim.x * 2) {
    float v = h[(size_t)r * 128 + c];
    s0 += v;
    s1 += v * v;
  }
  __shared__ float ls[256], lq[256];
  ls[threadIdx.x] = s0;
  lq[threadIdx.x] = s1;
  __syncthreads();
  if (threadIdx.x < 128) {
    atomicAdd(&sums[c], ls[threadIdx.x] + ls[threadIdx.x + 128]);
    atomicAdd(&sums[128 + c], lq[threadIdx.x] + lq[threadIdx.x + 128]);
  }
}

__global__ __launch_bounds__(256) void bn_apply(const float* __restrict__ h,
                                                u16* __restrict__ hbf,
                                                const float* __restrict__ sums,
                                                const float* __restrict__ gamma,
                                                const float* __restrict__ beta,
                                                float invN, int total) {
  __shared__ float sc[128], sh[128];
  int tid = threadIdx.x;
  if (tid < 128) {
    float mu = sums[tid] * invN;
    float var = sums[128 + tid] * invN - mu * mu;
    float inv = rsqrtf(var + 1e-5f);
    float s = gamma[tid] * inv;
    sc[tid] = s;
    sh[tid] = beta[tid] - mu * s;
  }
  __syncthreads();
  int i = blockIdx.x * 256 + tid;
  if (i < total) {
    int c = i & 127;
    hbf[i] = f2bf(h[i] * sc[c] + sh[c]);
  }
}

// ---------- launch ----------
extern "C" void kernel_launch(void* const* d_in, const int* in_sizes, int n_in,
                              void* d_out, int out_size, void* d_ws, size_t ws_size,
                              hipStream_t stream) {
  const float* x        = (const float*)d_in[0];
  const int*   ei0      = (const int*)d_in[1];
  const int*   et0      = (const int*)d_in[2];
  const int*   ei1      = (const int*)d_in[3];
  const int*   et1      = (const int*)d_in[4];
  const float* emb_type = (const float*)d_in[5];
  const float* emb_attr = (const float*)d_in[6];
  const float* v2e_Wq   = (const float*)d_in[7];
  const float* v2e_Wk   = (const float*)d_in[8];
  const float* v2e_Wv   = (const float*)d_in[9];
  const float* v2e_We   = (const float*)d_in[10];
  const float* v2e_Wsk  = (const float*)d_in[11];
  const float* e2_Wq    = (const float*)d_in[12];
  const float* e2_Wk    = (const float*)d_in[13];
  const float* e2_Wv    = (const float*)d_in[14];
  const float* e2_We    = (const float*)d_in[15];
  const float* e2_Wsk   = (const float*)d_in[16];
  const float* bn_gamma = (const float*)d_in[17];
  const float* bn_beta  = (const float*)d_in[18];
  float* out = (float*)d_out;

  // workspace layout
  char* wsb = (char*)d_ws;
  size_t off = 0;
  u16* xb  = (u16*)(wsb + off);  off += (size_t)NSRC * D * 2;
  u16* KVb = (u16*)(wsb + off);  off += (size_t)NSRC * D * 2 * 2;  // interleaved K|V
  u16* Qb  = (u16*)(wsb + off);  off += (size_t)NE0 * D * 2;
  u16* Sb  = (u16*)(wsb + off);  off += (size_t)NE0 * D * 2;
  float* hb = (float*)(wsb + off); off += (size_t)NE0 * D * 4;
  u16* hbf = (u16*)(wsb + off);  off += (size_t)NE0 * D * 2;
  u16* wtAll = (u16*)(wsb + off); off += 8 * 16384 * 2;
  int* elist = (int*)(wsb + off);  off += (size_t)ET * 4;
  int* rank  = (int*)(wsb + off);  off += (size_t)ET * 4;
  int* offs  = (int*)(wsb + off);  off += ((size_t)NT + 8) * 4;
  int* bsums = (int*)(wsb + off);  off += 1024;
  float* kv  = (float*)(wsb + off); off += 4 * 512 * 4;
  float* bnsums = (float*)(wsb + off); off += 256 * 4;  // sum[128] | sumsq[128]

  u16* wtK0 = wtAll + 0 * 16384;
  u16* wtV0 = wtAll + 1 * 16384;
  u16* wtQ0 = wtAll + 2 * 16384;
  u16* wtS0 = wtAll + 3 * 16384;
  u16* wtK1 = wtAll + 4 * 16384;
  u16* wtV1 = wtAll + 5 * 16384;
  u16* wtQ1 = wtAll + 6 * 16384;
  u16* wtS1 = wtAll + 7 * 16384;
  float* kep0 = kv;
  float* vep0 = kv + 512;
  float* kep1 = kv + 1024;
  float* vep1 = kv + 1536;

  const int* src0 = ei0;
  const int* dst0 = ei0 + E0N;
  const int* src1 = ei1;
  const int* dst1 = ei1 + E1N;

  // 1: mega-prep (cast + weights + embs + zeroing)
  prep_all<<<BC + 64 + 4 + BZ + 1, 256, 0, stream>>>(
      x, xb, v2e_Wk, v2e_Wv, v2e_Wq, v2e_Wsk, e2_Wk, e2_Wv, e2_Wq, e2_Wsk,
      wtAll, emb_type, emb_attr, v2e_We, e2_We, kv, offs, bnsums);

  // 2-6: CSR for both layers
  csr_count2<<<(ET + 255) / 256, 256, 0, stream>>>(dst0, dst1, offs, rank);
  {
    int nb = (NT + 1023) / 1024;
    scan1<<<nb, 256, 0, stream>>>(offs, offs, bsums, NT);
    scan2<<<1, 256, 0, stream>>>(bsums, nb);
    scan3<<<(NT + 255) / 256, 256, 0, stream>>>(offs, bsums, NT, ET);
  }
  csr_fill2<<<(ET + 255) / 256, 256, 0, stream>>>(dst0, src0, et0, dst1, src1, et1,
                                                  offs, rank, elist);

  // 7-10: layer 0
  {
    int nKV = (NSRC + 127) / 128, nQS = (NE0 + 127) / 128;
    gemm_quad<<<nKV + nQS, 512, 0, stream>>>(xb, wtK0, wtV0, KVb, NSRC, nKV,
                                             wtQ0, wtS0, Qb, Sb, NE0);
  }
  attn_fused<<<(NE0 + 15) / 16, 256, 0, stream>>>(elist, offs, Qb, KVb, kep0, vep0,
                                                  Sb, hb, NE0);
  bn_reduce<<<256, 256, 0, stream>>>(hb, bnsums, NE0);
  bn_apply<<<(NE0 * D + 255) / 256, 256, 0, stream>>>(hb, hbf, bnsums, bn_gamma, bn_beta,
                                                      1.0f / (float)NE0, NE0 * D);

  // 11-12: layer 1
  {
    int nKV = (NE0 + 127) / 128, nQS = (NE1 + 127) / 128;
    gemm_quad<<<nKV + nQS, 512, 0, stream>>>(hbf, wtK1, wtV1, KVb, NE0, nKV,
                                             wtQ1, wtS1, Qb, Sb, NE1);
  }
  attn_fused<<<(NE1 + 15) / 16, 256, 0, stream>>>(elist, offs + NE0, Qb, KVb, kep1, vep1,
                                                  Sb, out, NE1);
}

// Round 6
// 621.491 us; speedup vs baseline: 1.2682x; 1.0464x over previous
//
#include <hip/hip_runtime.h>
#include <cstdint>
#include <cstddef>

#define D 128
#define H 8
#define NSRC 200000
#define NE0  100000
#define NE1  50000
#define E0N  1000000
#define E1N  500000
#define NT   (NE0 + NE1)
#define ET   (E0N + E1N)

typedef unsigned short u16;
typedef __attribute__((ext_vector_type(8))) short short8;
typedef __attribute__((ext_vector_type(4))) float f32x4;
typedef __attribute__((ext_vector_type(2))) float f32x2;

// ---------- bf16 helpers ----------
__device__ __forceinline__ u16 f2bf(float f) {
  unsigned u = __float_as_uint(f);
  unsigned r = (u + 0x7fffu + ((u >> 16) & 1u)) >> 16;  // RNE
  return (u16)r;
}
__device__ __forceinline__ float bf2f(u16 u) {
  return __uint_as_float(((unsigned)u) << 16);
}
// unpack 2 packed bf16 (low = even dim) -> f32x2
__device__ __forceinline__ f32x2 unpk(unsigned u) {
  f32x2 r;
  r.x = __uint_as_float(u << 16);
  r.y = __uint_as_float(u & 0xffff0000u);
  return r;
}
// bf16 pair dot with f32 accumulate: d = a.lo*b.lo + a.hi*b.hi + c
__device__ __forceinline__ float dot2bf(unsigned a, unsigned b, float c) {
  float d;
  asm("v_dot2_f32_bf16 %0, %1, %2, %3" : "=v"(d) : "v"(a), "v"(b), "v"(c));
  return d;
}
__device__ __forceinline__ f32x2 fma2(f32x2 a, f32x2 b, f32x2 c) {
  return __builtin_elementwise_fma(a, b, c);
}

// ---------- mega-prep: x cast + weight transpose + emb GEMMs + zero-fill ----------
// block roles: [0,BC) cast | [BC,BC+64) weights | +4 embs | +BZ zero offs | +1 zero bn
#define BC 25000            // (NSRC*D/4)/256
#define BZ 147              // ceil((NT+1)/1024)
static_assert((size_t)BZ * 1024 >= NT + 1, "offs zero-fill must cover NT+1 entries");
__global__ __launch_bounds__(256) void prep_all(
    const float* __restrict__ x, u16* __restrict__ xb,
    const float* w0, const float* w1, const float* w2, const float* w3,
    const float* w4, const float* w5, const float* w6, const float* w7,
    u16* __restrict__ wt,
    const float* __restrict__ embA, const float* __restrict__ embB,
    const float* __restrict__ We0, const float* __restrict__ We1,
    float* __restrict__ kv,
    int* __restrict__ offs, float* __restrict__ bnsums) {
  int b = blockIdx.x;
  if (b < BC) {
    int i = b * 256 + threadIdx.x;
    float4 a = ((const float4*)x)[i];
    ushort4 o;
    o.x = f2bf(a.x); o.y = f2bf(a.y); o.z = f2bf(a.z); o.w = f2bf(a.w);
    ((ushort4*)xb)[i] = o;
  } else if (b < BC + 64) {
    int bb = b - BC;
    const float* wsrc[8] = {w0, w1, w2, w3, w4, w5, w6, w7};
    int mat = bb >> 3;
    int blk = bb & 7;
    const float* W = wsrc[mat];
    // fold 1/sqrt(d)=0.25 into Wq (mats 2 and 6) so Q comes out pre-scaled
    float sc = ((mat & 3) == 2) ? 0.25f : 1.0f;
    u16* out = wt + mat * 16384;
    for (int i = blk * 2048 + threadIdx.x; i < (blk + 1) * 2048; i += 256) {
      int n = i >> 7, k = i & 127;
      out[i] = f2bf(W[k * 128 + n] * sc);
    }
  } else if (b < BC + 68) {
    int bb = b - BC - 64;
    int mat = bb >> 1;
    int t = (bb & 1) * 256 + threadIdx.x;
    const float* We = mat ? We1 : We0;
    float* keOut = kv + mat * 1024;
    float* veOut = keOut + 512;
    int r = t >> 7, c = t & 127;
    float s0 = 0.f, s1 = 0.f;
    for (int k = 0; k < 128; ++k) {
      float w = We[k * 128 + c];
      s0 += embA[r * 128 + k] * w;
      s1 += embB[r * 128 + k] * w;
    }
    keOut[t] = s0;
    veOut[t] = s1;
  } else if (b < BC + 68 + BZ) {
    int base = (b - BC - 68) * 1024 + threadIdx.x * 4;
#pragma unroll
    for (int i = 0; i < 4; ++i)
      if (base + i < NT + 1) offs[base + i] = 0;
  } else {
    bnsums[threadIdx.x] = 0.f;  // 256 floats = bnsum|bnsq
  }
}

// ---------- quad-output MFMA GEMM, weights-in-LDS (R5, kept) ----------
__global__ __launch_bounds__(512, 4) void gemm_quad(
    const u16* __restrict__ A,
    const u16* __restrict__ WtK, const u16* __restrict__ WtV,
    u16* __restrict__ CKV, int NA, int nKV,
    const u16* __restrict__ WtQ, const u16* __restrict__ WtS,
    u16* __restrict__ CQ, u16* __restrict__ CS, int NB) {
  int bb = blockIdx.x;
  const u16 *Wt0, *Wt1;
  int N, tile0;
  bool ilv = (bb < nKV);
  if (ilv) {
    Wt0 = WtK; Wt1 = WtV; N = NA; tile0 = bb * 128;
  } else {
    Wt0 = WtQ; Wt1 = WtS; N = NB; tile0 = (bb - nKV) * 128;
  }
  int tid = threadIdx.x;
  int w = tid >> 6, lane = tid & 63;
  int g = w >> 1;          // row group: rows [g*32, g*32+32)
  int h = w & 1;           // feature half: features [h*64, h*64+64)
  int lrow = lane & 15, q = lane >> 4;

  __shared__ u16 Wls[2 * 128 * 128];  // 64 KB: both mats, chunk-XOR swizzled

  // 1) issue weight-staging loads FIRST (same 64 KB for all blocks -> L2-hot)
  uint4 wv[8];
#pragma unroll
  for (int i = 0; i < 8; ++i) {
    int m = i * 512 + tid;                       // 4096 x 16B chunks
    const u16* Wsrc = (m >> 11) ? Wt1 : Wt0;
    wv[i] = *(const uint4*)(Wsrc + (size_t)(m & 2047) * 8);
  }

  // 2) issue A-fragment loads (whole K-extent to regs); newer in VMEM FIFO,
  //    so staging's waitcnt leaves them in flight.
  int ra = tile0 + g * 32 + lrow;
  int rb = ra + 16;
  bool oka = ra < N, okb = rb < N;
  const u16* pa = A + (size_t)(oka ? ra : 0) * 128 + q * 8;
  const u16* pb = A + (size_t)(okb ? rb : 0) * 128 + q * 8;
  short8 av[4], bv[4];
#pragma unroll
  for (int kk = 0; kk < 4; ++kk) {
    av[kk] = *(const short8*)(pa + kk * 32);
    bv[kk] = *(const short8*)(pb + kk * 32);
  }

  // 3) LDS write (chunk-XOR swizzle: LDS(row,c) = W(row, c ^ (row&15)))
#pragma unroll
  for (int i = 0; i < 8; ++i) {
    int m = i * 512 + tid;
    int row = (m & 2047) >> 4, c = m & 15;
    *(uint4*)(Wls + (m >> 11) * 16384 + row * 128 + (c ^ (row & 15)) * 8) = wv[i];
  }
  __syncthreads();

  const u16* W0 = Wls + (h * 64) * 128;          // mat0, this wave's half
  const u16* W1 = Wls + 16384 + (h * 64) * 128;  // mat1, this wave's half

  f32x4 acc[2][2][4];  // [mat][rowset][j]
#pragma unroll
  for (int o = 0; o < 2; ++o)
#pragma unroll
    for (int i = 0; i < 2; ++i)
#pragma unroll
      for (int j = 0; j < 4; ++j) acc[o][i][j] = (f32x4){0.f, 0.f, 0.f, 0.f};

  const short8 zero8 = {0, 0, 0, 0, 0, 0, 0, 0};
#pragma unroll
  for (int kk = 0; kk < 4; ++kk) {
    short8 a0 = oka ? av[kk] : zero8;
    short8 a1 = okb ? bv[kk] : zero8;
    int cs = ((kk * 4 + q) ^ lrow) * 8;          // swizzled chunk offset
#pragma unroll
    for (int j = 0; j < 4; ++j) {
      int fr = j * 16 + lrow;                    // (global row &15) == lrow
      short8 b0 = *(const short8*)(W0 + fr * 128 + cs);
      short8 b1 = *(const short8*)(W1 + fr * 128 + cs);
      acc[0][0][j] = __builtin_amdgcn_mfma_f32_16x16x32_bf16(b0, a0, acc[0][0][j], 0, 0, 0);
      acc[0][1][j] = __builtin_amdgcn_mfma_f32_16x16x32_bf16(b0, a1, acc[0][1][j], 0, 0, 0);
      acc[1][0][j] = __builtin_amdgcn_mfma_f32_16x16x32_bf16(b1, a0, acc[1][0][j], 0, 0, 0);
      acc[1][1][j] = __builtin_amdgcn_mfma_f32_16x16x32_bf16(b1, a1, acc[1][1][j], 0, 0, 0);
    }
  }

  // epilogue: lane owns row (tile0 + g*32 + i*16 + lrow);
  // features f = h*64 + j*16 + q*4 + r (4 consecutive per acc quad)
  if (ilv) {
#pragma unroll
    for (int i = 0; i < 2; ++i) {
      int grow = tile0 + g * 32 + i * 16 + lrow;
      if (grow < N) {
#pragma unroll
        for (int o = 0; o < 2; ++o) {
          // u16 offset within row: (f>>3)*16 + (o<<3) + (f&7)
          // f>>3 = h*8 + 2j + (q>>1); f&7 start = (q&1)*4
          u16* base = CKV + (size_t)grow * 256 + (o << 3) + ((q & 1) << 2) +
                      ((q >> 1) << 4) + h * 128;
#pragma unroll
          for (int j = 0; j < 4; ++j) {
            f32x4 v = acc[o][i][j];
            ushort4 pk;
            pk.x = f2bf(v[0]); pk.y = f2bf(v[1]); pk.z = f2bf(v[2]); pk.w = f2bf(v[3]);
            *(ushort4*)(base + j * 32) = pk;
          }
        }
      }
    }
  } else {
#pragma unroll
    for (int o = 0; o < 2; ++o) {
      u16* C = o ? CS : CQ;
#pragma unroll
      for (int i = 0; i < 2; ++i) {
        int grow = tile0 + g * 32 + i * 16 + lrow;
        if (grow < N) {
          u16* base = C + (size_t)grow * 128 + q * 4 + h * 64;
#pragma unroll
          for (int j = 0; j < 4; ++j) {
            f32x4 v = acc[o][i][j];
            ushort4 pk;
            pk.x = f2bf(v[0]); pk.y = f2bf(v[1]); pk.z = f2bf(v[2]); pk.w = f2bf(v[3]);
            *(ushort4*)(base + j * 16) = pk;
          }
        }
      }
    }
  }
}

// ---------- CSR build (both layers, rank-based fill) ----------
__global__ __launch_bounds__(256) void csr_count2(
    const int* __restrict__ dst0, const int* __restrict__ dst1,
    int* __restrict__ cnt, int* __restrict__ rank) {
  int t = blockIdx.x * 256 + threadIdx.x;
  if (t < E0N) {
    rank[t] = atomicAdd(&cnt[dst0[t]], 1);
  } else if (t < ET) {
    rank[t] = atomicAdd(&cnt[NE0 + dst1[t - E0N]], 1);
  }
}

__global__ __launch_bounds__(256) void scan1(const int* __restrict__ cnt,
                                             int* __restrict__ excl,
                                             int* __restrict__ blocksums, int N) {
  __shared__ int sh[256];
  int tid = threadIdx.x;
  int base = blockIdx.x * 1024 + tid * 4;
  int v0 = (base + 0 < N) ? cnt[base + 0] : 0;
  int v1 = (base + 1 < N) ? cnt[base + 1] : 0;
  int v2 = (base + 2 < N) ? cnt[base + 2] : 0;
  int v3 = (base + 3 < N) ? cnt[base + 3] : 0;
  int tsum = v0 + v1 + v2 + v3;
  sh[tid] = tsum;
  __syncthreads();
  for (int off = 1; off < 256; off <<= 1) {
    int t2 = (tid >= off) ? sh[tid - off] : 0;
    __syncthreads();
    sh[tid] += t2;
    __syncthreads();
  }
  int incl = sh[tid];
  if (tid == 255) blocksums[blockIdx.x] = incl;
  int run = incl - tsum;
  if (base + 0 < N) excl[base + 0] = run; run += v0;
  if (base + 1 < N) excl[base + 1] = run; run += v1;
  if (base + 2 < N) excl[base + 2] = run; run += v2;
  if (base + 3 < N) excl[base + 3] = run;
}

__global__ void scan2(int* __restrict__ blocksums, int nb) {
  __shared__ int sh[256];
  int tid = threadIdx.x;
  int v = (tid < nb) ? blocksums[tid] : 0;
  sh[tid] = v;
  __syncthreads();
  for (int off = 1; off < 256; off <<= 1) {
    int t2 = (tid >= off) ? sh[tid - off] : 0;
    __syncthreads();
    sh[tid] += t2;
    __syncthreads();
  }
  if (tid < nb) blocksums[tid] = sh[tid] - v;
}

__global__ __launch_bounds__(256) void scan3(int* __restrict__ offs,
                                             const int* __restrict__ blocksums, int N,
                                             int Etot) {
  int t = blockIdx.x * 256 + threadIdx.x;
  if (t < N) offs[t] += blocksums[t >> 10];
  if (t == 0) offs[N] = Etot;
}

__global__ __launch_bounds__(256) void csr_fill2(
    const int* __restrict__ dst0, const int* __restrict__ src0, const int* __restrict__ et0,
    const int* __restrict__ dst1, const int* __restrict__ src1, const int* __restrict__ et1,
    const int* __restrict__ offs, const int* __restrict__ rank,
    int* __restrict__ elist) {
  int t = blockIdx.x * 256 + threadIdx.x;
  if (t < E0N) {
    int p = offs[dst0[t]] + rank[t];
    elist[p] = (src0[t] << 2) | et0[t];
  } else if (t < ET) {
    int t2 = t - E0N;
    int p = offs[NE0 + dst1[t2]] + rank[t];
    elist[p] = (src1[t2] << 2) | et1[t2];
  }
}

// ---------- fused flash attention + skip combine (R6: 2-deep pipeline) ------
// R5 post-mortem: V-gathers were issued+consumed in the SAME iteration (~130
// cyc cover vs ~500 cyc L3 gather latency) and elist->KV was a serial chain
// within the iteration. Fix: full double-buffer. Per iteration: issue K AND V
// for batch j+4 using codes already resident (loaded last iteration); load
// codes for batch j+8; compute batch j from fully-resident K/V. Every gather
// gets a whole iteration of cover; codes->gather dependence spans iterations.
// 4 dsts/wave, 16 lanes/dst, 8 consecutive dims/lane; KV row = 16 x {K8|V8}.
__device__ __forceinline__ float sel4(float s0, float s1, float s2, float s3, int ty) {
  float a = (ty & 1) ? s1 : s0;
  float b = (ty & 1) ? s3 : s2;
  return (ty & 2) ? b : a;
}

__global__ __launch_bounds__(256) void attn_fused(
    const int* __restrict__ elist, const int* __restrict__ offs,
    const u16* __restrict__ Q, const u16* __restrict__ KV,
    const float* __restrict__ ke, const float* __restrict__ ve,
    const u16* __restrict__ skipb, float* __restrict__ outp, int N) {
  int wave = (blockIdx.x * 256 + threadIdx.x) >> 6;
  int lane = threadIdx.x & 63;
  int which = lane >> 4;   // dst slot within wave
  int sub = lane & 15;     // 16 lanes per dst
  int d = wave * 4 + which;
  bool active = d < N;
  int dc = active ? d : 0;
  int dim0 = sub * 8;      // 8 consecutive dims per lane; head = sub>>1
  int sub16 = sub * 16;    // u16 offset of this lane's group within a KV row

  // Q: 8 dims as 4 packed bf16 pairs (already scaled by 1/sqrt(d))
  uint4 qp = *(const uint4*)(Q + (size_t)dc * D + dim0);
  f32x2 u0 = unpk(qp.x), u1 = unpk(qp.y), u2 = unpk(qp.z), u3 = unpk(qp.w);

  // per-type q . (We ek) : reduce over head (2 lanes)
  float qk0, qk1, qk2, qk3;
#pragma unroll
  for (int ty = 0; ty < 4; ++ty) {
    const float* kt = ke + ty * D + dim0;
    float4 ka = *(const float4*)kt;
    float4 kb = *(const float4*)(kt + 4);
    float p = u0.x * ka.x + u0.y * ka.y + u1.x * ka.z + u1.y * ka.w +
              u2.x * kb.x + u2.y * kb.y + u3.x * kb.z + u3.y * kb.w;
    p += __shfl_xor(p, 1, 64);
    if (ty == 0) qk0 = p; else if (ty == 1) qk1 = p; else if (ty == 2) qk2 = p; else qk3 = p;
  }

  int j0 = active ? offs[d] : 0;
  int j1 = active ? offs[d + 1] : 0;
  int j = j0;

  // --- pipeline prologue ---
  // codes for current batch (j) and next batch (j+4)
  int cp0, cp1, cp2, cp3;      // current
  int fp0, fp1, fp2, fp3;      // future (j+4)
  {
    int i0 = (j + 0 < j1) ? j + 0 : 0;
    int i1 = (j + 1 < j1) ? j + 1 : 0;
    int i2 = (j + 2 < j1) ? j + 2 : 0;
    int i3 = (j + 3 < j1) ? j + 3 : 0;
    cp0 = elist[i0]; cp1 = elist[i1]; cp2 = elist[i2]; cp3 = elist[i3];
    int k0 = (j + 4 < j1) ? j + 4 : 0;
    int k1 = (j + 5 < j1) ? j + 5 : 0;
    int k2 = (j + 6 < j1) ? j + 6 : 0;
    int k3 = (j + 7 < j1) ? j + 7 : 0;
    fp0 = elist[k0]; fp1 = elist[k1]; fp2 = elist[k2]; fp3 = elist[k3];
  }
  // K+V for current batch (one-time exposed latency)
  uint4 ck0 = *(const uint4*)(KV + (size_t)(cp0 >> 2) * 256 + sub16);
  uint4 ck1 = *(const uint4*)(KV + (size_t)(cp1 >> 2) * 256 + sub16);
  uint4 ck2 = *(const uint4*)(KV + (size_t)(cp2 >> 2) * 256 + sub16);
  uint4 ck3 = *(const uint4*)(KV + (size_t)(cp3 >> 2) * 256 + sub16);
  uint4 cw0 = *(const uint4*)(KV + (size_t)(cp0 >> 2) * 256 + sub16 + 8);
  uint4 cw1 = *(const uint4*)(KV + (size_t)(cp1 >> 2) * 256 + sub16 + 8);
  uint4 cw2 = *(const uint4*)(KV + (size_t)(cp2 >> 2) * 256 + sub16 + 8);
  uint4 cw3 = *(const uint4*)(KV + (size_t)(cp3 >> 2) * 256 + sub16 + 8);

  float m = -INFINITY, s = 0.f;
  f32x2 acc01 = {0.f, 0.f}, acc23 = {0.f, 0.f}, acc45 = {0.f, 0.f}, acc67 = {0.f, 0.f};

  while (__any(j < j1)) {
    int jn = j + 4;
    // issue K+V for NEXT batch (codes fp* already resident -> no chain)
    uint4 nk0 = *(const uint4*)(KV + (size_t)(fp0 >> 2) * 256 + sub16);
    uint4 nk1 = *(const uint4*)(KV + (size_t)(fp1 >> 2) * 256 + sub16);
    uint4 nk2 = *(const uint4*)(KV + (size_t)(fp2 >> 2) * 256 + sub16);
    uint4 nk3 = *(const uint4*)(KV + (size_t)(fp3 >> 2) * 256 + sub16);
    uint4 nw0 = *(const uint4*)(KV + (size_t)(fp0 >> 2) * 256 + sub16 + 8);
    uint4 nw1 = *(const uint4*)(KV + (size_t)(fp1 >> 2) * 256 + sub16 + 8);
    uint4 nw2 = *(const uint4*)(KV + (size_t)(fp2 >> 2) * 256 + sub16 + 8);
    uint4 nw3 = *(const uint4*)(KV + (size_t)(fp3 >> 2) * 256 + sub16 + 8);
    // load codes for batch j+8 (consumed next iteration)
    int g0 = (jn + 4 < j1) ? jn + 4 : 0;
    int g1 = (jn + 5 < j1) ? jn + 5 : 0;
    int g2 = (jn + 6 < j1) ? jn + 6 : 0;
    int g3 = (jn + 7 < j1) ? jn + 7 : 0;
    int gp0 = elist[g0], gp1 = elist[g1], gp2 = elist[g2], gp3 = elist[g3];

    int n = j1 - j;
    if (n > 0) {
      int t0 = cp0 & 3, t1 = cp1 & 3, t2 = cp2 & 3, t3 = cp3 & 3;
      const float* vp0 = ve + t0 * D + dim0;
      const float* vp1 = ve + t1 * D + dim0;
      const float* vp2 = ve + t2 * D + dim0;
      const float* vp3 = ve + t3 * D + dim0;
      float4 va0 = *(const float4*)vp0, vb0 = *(const float4*)(vp0 + 4);
      float4 va1 = *(const float4*)vp1, vb1 = *(const float4*)(vp1 + 4);
      float4 va2 = *(const float4*)vp2, vb2 = *(const float4*)(vp2 + 4);
      float4 va3 = *(const float4*)vp3, vb3 = *(const float4*)(vp3 + 4);

      // q . k over lane's 8 dims (bf16 dot2), then head-reduce over 2 lanes
      float p0 = dot2bf(qp.x, ck0.x, dot2bf(qp.y, ck0.y, dot2bf(qp.z, ck0.z, dot2bf(qp.w, ck0.w, 0.f))));
      float p1 = dot2bf(qp.x, ck1.x, dot2bf(qp.y, ck1.y, dot2bf(qp.z, ck1.z, dot2bf(qp.w, ck1.w, 0.f))));
      float p2 = dot2bf(qp.x, ck2.x, dot2bf(qp.y, ck2.y, dot2bf(qp.z, ck2.z, dot2bf(qp.w, ck2.w, 0.f))));
      float p3 = dot2bf(qp.x, ck3.x, dot2bf(qp.y, ck3.y, dot2bf(qp.z, ck3.z, dot2bf(qp.w, ck3.w, 0.f))));
      p0 += __shfl_xor(p0, 1, 64);
      p1 += __shfl_xor(p1, 1, 64);
      p2 += __shfl_xor(p2, 1, 64);
      p3 += __shfl_xor(p3, 1, 64);

      float l0 = p0 + sel4(qk0, qk1, qk2, qk3, t0);
      float l1 = p1 + sel4(qk0, qk1, qk2, qk3, t1);
      float l2 = p2 + sel4(qk0, qk1, qk2, qk3, t2);
      float l3 = p3 + sel4(qk0, qk1, qk2, qk3, t3);
      l0 = l0 >= 0.f ? l0 : 0.2f * l0;
      l1 = l1 >= 0.f ? l1 : 0.2f * l1;
      l2 = l2 >= 0.f ? l2 : 0.2f * l2;
      l3 = l3 >= 0.f ? l3 : 0.2f * l3;
      if (n < 2) l1 = -INFINITY;
      if (n < 3) l2 = -INFINITY;
      if (n < 4) l3 = -INFINITY;
      float mb = fmaxf(fmaxf(l0, l1), fmaxf(l2, l3));
      float mn = fmaxf(m, mb);
      float f = __expf(m - mn);
      float a0 = __expf(l0 - mn);
      float a1 = __expf(l1 - mn);
      float a2 = __expf(l2 - mn);
      float a3 = __expf(l3 - mn);
      s = s * f + ((a0 + a1) + (a2 + a3));
      f32x2 ff = {f, f};
      acc01 *= ff; acc23 *= ff; acc45 *= ff; acc67 *= ff;
      f32x2 aa0 = {a0, a0}, aa1 = {a1, a1}, aa2 = {a2, a2}, aa3 = {a3, a3};
      acc01 = fma2(aa0, unpk(cw0.x) + (f32x2){va0.x, va0.y}, acc01);
      acc23 = fma2(aa0, unpk(cw0.y) + (f32x2){va0.z, va0.w}, acc23);
      acc45 = fma2(aa0, unpk(cw0.z) + (f32x2){vb0.x, vb0.y}, acc45);
      acc67 = fma2(aa0, unpk(cw0.w) + (f32x2){vb0.z, vb0.w}, acc67);
      acc01 = fma2(aa1, unpk(cw1.x) + (f32x2){va1.x, va1.y}, acc01);
      acc23 = fma2(aa1, unpk(cw1.y) + (f32x2){va1.z, va1.w}, acc23);
      acc45 = fma2(aa1, unpk(cw1.z) + (f32x2){vb1.x, vb1.y}, acc45);
      acc67 = fma2(aa1, unpk(cw1.w) + (f32x2){vb1.z, vb1.w}, acc67);
      acc01 = fma2(aa2, unpk(cw2.x) + (f32x2){va2.x, va2.y}, acc01);
      acc23 = fma2(aa2, unpk(cw2.y) + (f32x2){va2.z, va2.w}, acc23);
      acc45 = fma2(aa2, unpk(cw2.z) + (f32x2){vb2.x, vb2.y}, acc45);
      acc67 = fma2(aa2, unpk(cw2.w) + (f32x2){vb2.z, vb2.w}, acc67);
      acc01 = fma2(aa3, unpk(cw3.x) + (f32x2){va3.x, va3.y}, acc01);
      acc23 = fma2(aa3, unpk(cw3.y) + (f32x2){va3.z, va3.w}, acc23);
      acc45 = fma2(aa3, unpk(cw3.z) + (f32x2){vb3.x, vb3.y}, acc45);
      acc67 = fma2(aa3, unpk(cw3.w) + (f32x2){vb3.z, vb3.w}, acc67);
      m = mn;
    }
    // rotate pipeline
    cp0 = fp0; cp1 = fp1; cp2 = fp2; cp3 = fp3;
    fp0 = gp0; fp1 = gp1; fp2 = gp2; fp3 = gp3;
    ck0 = nk0; ck1 = nk1; ck2 = nk2; ck3 = nk3;
    cw0 = nw0; cw1 = nw1; cw2 = nw2; cw3 = nw3;
    j = jn;
  }
  if (active) {
    float inv = 1.f / (s + 1e-16f);
    float hf = 0.5f * inv;
    uint4 sk = *(const uint4*)(skipb + (size_t)d * D + dim0);
    f32x2 s0 = unpk(sk.x), s1 = unpk(sk.y), s2 = unpk(sk.z), s3 = unpk(sk.w);
    float* op = outp + (size_t)d * D + dim0;
    float4 o0, o1;
    o0.x = 0.5f * s0.x + hf * acc01.x;
    o0.y = 0.5f * s0.y + hf * acc01.y;
    o0.z = 0.5f * s1.x + hf * acc23.x;
    o0.w = 0.5f * s1.y + hf * acc23.y;
    o1.x = 0.5f * s2.x + hf * acc45.x;
    o1.y = 0.5f * s2.y + hf * acc45.y;
    o1.z = 0.5f * s3.x + hf * acc67.x;
    o1.w = 0.5f * s3.y + hf * acc67.y;
    *(float4*)op = o0;
    *(float4*)(op + 4) = o1;
  }
}

// ---------- batch norm ----------
__global__ __launch_bounds__(256) void bn_reduce(const float* __restrict__ h,
                                                 float* __restrict__ sums, int N) {
  int c = threadIdx.x & 127;
  int rofs = threadIdx.x >> 7;
  float s0 = 0.f, s1 = 0.f;
  for (int r = blockIdx.x * 2 + rofs; r < N; r += gridDim.x * 2) {
    float v = h[(size_t)r * 128 + c];
    s0 += v;
    s1 += v * v;
  }
  __shared__ float ls[256], lq[256];
  ls[threadIdx.x] = s0;
  lq[threadIdx.x] = s1;
  __syncthreads();
  if (threadIdx.x < 128) {
    atomicAdd(&sums[c], ls[threadIdx.x] + ls[threadIdx.x + 128]);
    atomicAdd(&sums[128 + c], lq[threadIdx.x] + lq[threadIdx.x + 128]);
  }
}

__global__ __launch_bounds__(256) void bn_apply(const float* __restrict__ h,
                                                u16* __restrict__ hbf,
                                                const float* __restrict__ sums,
                                                const float* __restrict__ gamma,
                                                const float* __restrict__ beta,
                                                float invN, int total) {
  __shared__ float sc[128], sh[128];
  int tid = threadIdx.x;
  if (tid < 128) {
    float mu = sums[tid] * invN;
    float var = sums[128 + tid] * invN - mu * mu;
    float inv = rsqrtf(var + 1e-5f);
    float s = gamma[tid] * inv;
    sc[tid] = s;
    sh[tid] = beta[tid] - mu * s;
  }
  __syncthreads();
  int i = blockIdx.x * 256 + tid;
  if (i < total) {
    int c = i & 127;
    hbf[i] = f2bf(h[i] * sc[c] + sh[c]);
  }
}

// ---------- launch ----------
extern "C" void kernel_launch(void* const* d_in, const int* in_sizes, int n_in,
                              void* d_out, int out_size, void* d_ws, size_t ws_size,
                              hipStream_t stream) {
  const float* x        = (const float*)d_in[0];
  const int*   ei0      = (const int*)d_in[1];
  const int*   et0      = (const int*)d_in[2];
  const int*   ei1      = (const int*)d_in[3];
  const int*   et1      = (const int*)d_in[4];
  const float* emb_type = (const float*)d_in[5];
  const float* emb_attr = (const float*)d_in[6];
  const float* v2e_Wq   = (const float*)d_in[7];
  const float* v2e_Wk   = (const float*)d_in[8];
  const float* v2e_Wv   = (const float*)d_in[9];
  const float* v2e_We   = (const float*)d_in[10];
  const float* v2e_Wsk  = (const float*)d_in[11];
  const float* e2_Wq    = (const float*)d_in[12];
  const float* e2_Wk    = (const float*)d_in[13];
  const float* e2_Wv    = (const float*)d_in[14];
  const float* e2_We    = (const float*)d_in[15];
  const float* e2_Wsk   = (const float*)d_in[16];
  const float* bn_gamma = (const float*)d_in[17];
  const float* bn_beta  = (const float*)d_in[18];
  float* out = (float*)d_out;

  // workspace layout
  char* wsb = (char*)d_ws;
  size_t off = 0;
  u16* xb  = (u16*)(wsb + off);  off += (size_t)NSRC * D * 2;
  u16* KVb = (u16*)(wsb + off);  off += (size_t)NSRC * D * 2 * 2;  // interleaved K|V
  u16* Qb  = (u16*)(wsb + off);  off += (size_t)NE0 * D * 2;
  u16* Sb  = (u16*)(wsb + off);  off += (size_t)NE0 * D * 2;
  float* hb = (float*)(wsb + off); off += (size_t)NE0 * D * 4;
  u16* hbf = (u16*)(wsb + off);  off += (size_t)NE0 * D * 2;
  u16* wtAll = (u16*)(wsb + off); off += 8 * 16384 * 2;
  int* elist = (int*)(wsb + off);  off += (size_t)ET * 4;
  int* rank  = (int*)(wsb + off);  off += (size_t)ET * 4;
  int* offs  = (int*)(wsb + off);  off += ((size_t)NT + 8) * 4;
  int* bsums = (int*)(wsb + off);  off += 1024;
  float* kv  = (float*)(wsb + off); off += 4 * 512 * 4;
  float* bnsums = (float*)(wsb + off); off += 256 * 4;  // sum[128] | sumsq[128]

  u16* wtK0 = wtAll + 0 * 16384;
  u16* wtV0 = wtAll + 1 * 16384;
  u16* wtQ0 = wtAll + 2 * 16384;
  u16* wtS0 = wtAll + 3 * 16384;
  u16* wtK1 = wtAll + 4 * 16384;
  u16* wtV1 = wtAll + 5 * 16384;
  u16* wtQ1 = wtAll + 6 * 16384;
  u16* wtS1 = wtAll + 7 * 16384;
  float* kep0 = kv;
  float* vep0 = kv + 512;
  float* kep1 = kv + 1024;
  float* vep1 = kv + 1536;

  const int* src0 = ei0;
  const int* dst0 = ei0 + E0N;
  const int* src1 = ei1;
  const int* dst1 = ei1 + E1N;

  // 1: mega-prep (cast + weights + embs + zeroing)
  prep_all<<<BC + 64 + 4 + BZ + 1, 256, 0, stream>>>(
      x, xb, v2e_Wk, v2e_Wv, v2e_Wq, v2e_Wsk, e2_Wk, e2_Wv, e2_Wq, e2_Wsk,
      wtAll, emb_type, emb_attr, v2e_We, e2_We, kv, offs, bnsums);

  // 2-6: CSR for both layers
  csr_count2<<<(ET + 255) / 256, 256, 0, stream>>>(dst0, dst1, offs, rank);
  {
    int nb = (NT + 1023) / 1024;
    scan1<<<nb, 256, 0, stream>>>(offs, offs, bsums, NT);
    scan2<<<1, 256, 0, stream>>>(bsums, nb);
    scan3<<<(NT + 255) / 256, 256, 0, stream>>>(offs, bsums, NT, ET);
  }
  csr_fill2<<<(ET + 255) / 256, 256, 0, stream>>>(dst0, src0, et0, dst1, src1, et1,
                                                  offs, rank, elist);

  // 7-10: layer 0
  {
    int nKV = (NSRC + 127) / 128, nQS = (NE0 + 127) / 128;
    gemm_quad<<<nKV + nQS, 512, 0, stream>>>(xb, wtK0, wtV0, KVb, NSRC, nKV,
                                             wtQ0, wtS0, Qb, Sb, NE0);
  }
  attn_fused<<<(NE0 + 15) / 16, 256, 0, stream>>>(elist, offs, Qb, KVb, kep0, vep0,
                                                  Sb, hb, NE0);
  bn_reduce<<<256, 256, 0, stream>>>(hb, bnsums, NE0);
  bn_apply<<<(NE0 * D + 255) / 256, 256, 0, stream>>>(hb, hbf, bnsums, bn_gamma, bn_beta,
                                                      1.0f / (float)NE0, NE0 * D);

  // 11-12: layer 1
  {
    int nKV = (NE0 + 127) / 128, nQS = (NE1 + 127) / 128;
    gemm_quad<<<nKV + nQS, 512, 0, stream>>>(hbf, wtK1, wtV1, KVb, NE0, nKV,
                                             wtQ1, wtS1, Qb, Sb, NE1);
  }
  attn_fused<<<(NE1 + 15) / 16, 256, 0, stream>>>(elist, offs + NE0, Qb, KVb, kep1, vep1,
                                                  Sb, out, NE1);
}

// Round 7
// 618.565 us; speedup vs baseline: 1.2742x; 1.0047x over previous
//
#include <hip/hip_runtime.h>
#include <cstdint>
#include <cstddef>

#define D 128
#define H 8
#define NSRC 200000
#define NE0  100000
#define NE1  50000
#define E0N  1000000
#define E1N  500000
#define NT   (NE0 + NE1)
#define ET   (E0N + E1N)

typedef unsigned short u16;
typedef __attribute__((ext_vector_type(8))) short short8;
typedef __attribute__((ext_vector_type(4))) float f32x4;
typedef __attribute__((ext_vector_type(2))) float f32x2;

// ---------- bf16 helpers ----------
__device__ __forceinline__ u16 f2bf(float f) {
  unsigned u = __float_as_uint(f);
  unsigned r = (u + 0x7fffu + ((u >> 16) & 1u)) >> 16;  // RNE
  return (u16)r;
}
__device__ __forceinline__ float bf2f(u16 u) {
  return __uint_as_float(((unsigned)u) << 16);
}
// unpack 2 packed bf16 (low = even dim) -> f32x2
__device__ __forceinline__ f32x2 unpk(unsigned u) {
  f32x2 r;
  r.x = __uint_as_float(u << 16);
  r.y = __uint_as_float(u & 0xffff0000u);
  return r;
}
// bf16 pair dot with f32 accumulate: d = a.lo*b.lo + a.hi*b.hi + c
__device__ __forceinline__ float dot2bf(unsigned a, unsigned b, float c) {
  float d;
  asm("v_dot2_f32_bf16 %0, %1, %2, %3" : "=v"(d) : "v"(a), "v"(b), "v"(c));
  return d;
}
__device__ __forceinline__ f32x2 fma2(f32x2 a, f32x2 b, f32x2 c) {
  return __builtin_elementwise_fma(a, b, c);
}

// ---------- mega-prep: x cast + weight transpose + emb GEMMs + zero-fill ----------
// block roles: [0,BC) cast | [BC,BC+64) weights | +4 embs | +BZ zero offs | +1 zero bn
#define BC 25000            // (NSRC*D/4)/256
#define BZ 147              // ceil((NT+1)/1024)
static_assert((size_t)BZ * 1024 >= NT + 1, "offs zero-fill must cover NT+1 entries");
__global__ __launch_bounds__(256) void prep_all(
    const float* __restrict__ x, u16* __restrict__ xb,
    const float* w0, const float* w1, const float* w2, const float* w3,
    const float* w4, const float* w5, const float* w6, const float* w7,
    u16* __restrict__ wt,
    const float* __restrict__ embA, const float* __restrict__ embB,
    const float* __restrict__ We0, const float* __restrict__ We1,
    float* __restrict__ kv,
    int* __restrict__ offs, float* __restrict__ bnsums) {
  int b = blockIdx.x;
  if (b < BC) {
    int i = b * 256 + threadIdx.x;
    float4 a = ((const float4*)x)[i];
    ushort4 o;
    o.x = f2bf(a.x); o.y = f2bf(a.y); o.z = f2bf(a.z); o.w = f2bf(a.w);
    ((ushort4*)xb)[i] = o;
  } else if (b < BC + 64) {
    int bb = b - BC;
    const float* wsrc[8] = {w0, w1, w2, w3, w4, w5, w6, w7};
    int mat = bb >> 3;
    int blk = bb & 7;
    const float* W = wsrc[mat];
    // fold 1/sqrt(d)=0.25 into Wq (mats 2 and 6) so Q comes out pre-scaled
    float sc = ((mat & 3) == 2) ? 0.25f : 1.0f;
    u16* out = wt + mat * 16384;
    for (int i = blk * 2048 + threadIdx.x; i < (blk + 1) * 2048; i += 256) {
      int n = i >> 7, k = i & 127;
      out[i] = f2bf(W[k * 128 + n] * sc);
    }
  } else if (b < BC + 68) {
    int bb = b - BC - 64;
    int mat = bb >> 1;
    int t = (bb & 1) * 256 + threadIdx.x;
    const float* We = mat ? We1 : We0;
    float* keOut = kv + mat * 1024;
    float* veOut = keOut + 512;
    int r = t >> 7, c = t & 127;
    float s0 = 0.f, s1 = 0.f;
    for (int k = 0; k < 128; ++k) {
      float w = We[k * 128 + c];
      s0 += embA[r * 128 + k] * w;
      s1 += embB[r * 128 + k] * w;
    }
    keOut[t] = s0;
    veOut[t] = s1;
  } else if (b < BC + 68 + BZ) {
    int base = (b - BC - 68) * 1024 + threadIdx.x * 4;
#pragma unroll
    for (int i = 0; i < 4; ++i)
      if (base + i < NT + 1) offs[base + i] = 0;
  } else {
    bnsums[threadIdx.x] = 0.f;  // 256 floats = bnsum|bnsq
  }
}

// ---------- quad-output MFMA GEMM, weights-in-LDS (R5, kept) ----------
__global__ __launch_bounds__(512, 4) void gemm_quad(
    const u16* __restrict__ A,
    const u16* __restrict__ WtK, const u16* __restrict__ WtV,
    u16* __restrict__ CKV, int NA, int nKV,
    const u16* __restrict__ WtQ, const u16* __restrict__ WtS,
    u16* __restrict__ CQ, u16* __restrict__ CS, int NB) {
  int bb = blockIdx.x;
  const u16 *Wt0, *Wt1;
  int N, tile0;
  bool ilv = (bb < nKV);
  if (ilv) {
    Wt0 = WtK; Wt1 = WtV; N = NA; tile0 = bb * 128;
  } else {
    Wt0 = WtQ; Wt1 = WtS; N = NB; tile0 = (bb - nKV) * 128;
  }
  int tid = threadIdx.x;
  int w = tid >> 6, lane = tid & 63;
  int g = w >> 1;          // row group: rows [g*32, g*32+32)
  int h = w & 1;           // feature half: features [h*64, h*64+64)
  int lrow = lane & 15, q = lane >> 4;

  __shared__ u16 Wls[2 * 128 * 128];  // 64 KB: both mats, chunk-XOR swizzled

  // 1) issue weight-staging loads FIRST (same 64 KB for all blocks -> L2-hot)
  uint4 wv[8];
#pragma unroll
  for (int i = 0; i < 8; ++i) {
    int m = i * 512 + tid;                       // 4096 x 16B chunks
    const u16* Wsrc = (m >> 11) ? Wt1 : Wt0;
    wv[i] = *(const uint4*)(Wsrc + (size_t)(m & 2047) * 8);
  }

  // 2) issue A-fragment loads (whole K-extent to regs); newer in VMEM FIFO,
  //    so staging's waitcnt leaves them in flight.
  int ra = tile0 + g * 32 + lrow;
  int rb = ra + 16;
  bool oka = ra < N, okb = rb < N;
  const u16* pa = A + (size_t)(oka ? ra : 0) * 128 + q * 8;
  const u16* pb = A + (size_t)(okb ? rb : 0) * 128 + q * 8;
  short8 av[4], bv[4];
#pragma unroll
  for (int kk = 0; kk < 4; ++kk) {
    av[kk] = *(const short8*)(pa + kk * 32);
    bv[kk] = *(const short8*)(pb + kk * 32);
  }

  // 3) LDS write (chunk-XOR swizzle: LDS(row,c) = W(row, c ^ (row&15)))
#pragma unroll
  for (int i = 0; i < 8; ++i) {
    int m = i * 512 + tid;
    int row = (m & 2047) >> 4, c = m & 15;
    *(uint4*)(Wls + (m >> 11) * 16384 + row * 128 + (c ^ (row & 15)) * 8) = wv[i];
  }
  __syncthreads();

  const u16* W0 = Wls + (h * 64) * 128;          // mat0, this wave's half
  const u16* W1 = Wls + 16384 + (h * 64) * 128;  // mat1, this wave's half

  f32x4 acc[2][2][4];  // [mat][rowset][j]
#pragma unroll
  for (int o = 0; o < 2; ++o)
#pragma unroll
    for (int i = 0; i < 2; ++i)
#pragma unroll
      for (int j = 0; j < 4; ++j) acc[o][i][j] = (f32x4){0.f, 0.f, 0.f, 0.f};

  const short8 zero8 = {0, 0, 0, 0, 0, 0, 0, 0};
#pragma unroll
  for (int kk = 0; kk < 4; ++kk) {
    short8 a0 = oka ? av[kk] : zero8;
    short8 a1 = okb ? bv[kk] : zero8;
    int cs = ((kk * 4 + q) ^ lrow) * 8;          // swizzled chunk offset
#pragma unroll
    for (int j = 0; j < 4; ++j) {
      int fr = j * 16 + lrow;                    // (global row &15) == lrow
      short8 b0 = *(const short8*)(W0 + fr * 128 + cs);
      short8 b1 = *(const short8*)(W1 + fr * 128 + cs);
      acc[0][0][j] = __builtin_amdgcn_mfma_f32_16x16x32_bf16(b0, a0, acc[0][0][j], 0, 0, 0);
      acc[0][1][j] = __builtin_amdgcn_mfma_f32_16x16x32_bf16(b0, a1, acc[0][1][j], 0, 0, 0);
      acc[1][0][j] = __builtin_amdgcn_mfma_f32_16x16x32_bf16(b1, a0, acc[1][0][j], 0, 0, 0);
      acc[1][1][j] = __builtin_amdgcn_mfma_f32_16x16x32_bf16(b1, a1, acc[1][1][j], 0, 0, 0);
    }
  }

  // epilogue: lane owns row (tile0 + g*32 + i*16 + lrow);
  // features f = h*64 + j*16 + q*4 + r (4 consecutive per acc quad)
  if (ilv) {
#pragma unroll
    for (int i = 0; i < 2; ++i) {
      int grow = tile0 + g * 32 + i * 16 + lrow;
      if (grow < N) {
#pragma unroll
        for (int o = 0; o < 2; ++o) {
          // u16 offset within row: (f>>3)*16 + (o<<3) + (f&7)
          // f>>3 = h*8 + 2j + (q>>1); f&7 start = (q&1)*4
          u16* base = CKV + (size_t)grow * 256 + (o << 3) + ((q & 1) << 2) +
                      ((q >> 1) << 4) + h * 128;
#pragma unroll
          for (int j = 0; j < 4; ++j) {
            f32x4 v = acc[o][i][j];
            ushort4 pk;
            pk.x = f2bf(v[0]); pk.y = f2bf(v[1]); pk.z = f2bf(v[2]); pk.w = f2bf(v[3]);
            *(ushort4*)(base + j * 32) = pk;
          }
        }
      }
    }
  } else {
#pragma unroll
    for (int o = 0; o < 2; ++o) {
      u16* C = o ? CS : CQ;
#pragma unroll
      for (int i = 0; i < 2; ++i) {
        int grow = tile0 + g * 32 + i * 16 + lrow;
        if (grow < N) {
          u16* base = C + (size_t)grow * 128 + q * 4 + h * 64;
#pragma unroll
          for (int j = 0; j < 4; ++j) {
            f32x4 v = acc[o][i][j];
            ushort4 pk;
            pk.x = f2bf(v[0]); pk.y = f2bf(v[1]); pk.z = f2bf(v[2]); pk.w = f2bf(v[3]);
            *(ushort4*)(base + j * 16) = pk;
          }
        }
      }
    }
  }
}

// ---------- CSR build (both layers, rank-based fill) ----------
__global__ __launch_bounds__(256) void csr_count2(
    const int* __restrict__ dst0, const int* __restrict__ dst1,
    int* __restrict__ cnt, int* __restrict__ rank) {
  int t = blockIdx.x * 256 + threadIdx.x;
  if (t < E0N) {
    rank[t] = atomicAdd(&cnt[dst0[t]], 1);
  } else if (t < ET) {
    rank[t] = atomicAdd(&cnt[NE0 + dst1[t - E0N]], 1);
  }
}

__global__ __launch_bounds__(256) void scan1(const int* __restrict__ cnt,
                                             int* __restrict__ excl,
                                             int* __restrict__ blocksums, int N) {
  __shared__ int sh[256];
  int tid = threadIdx.x;
  int base = blockIdx.x * 1024 + tid * 4;
  int v0 = (base + 0 < N) ? cnt[base + 0] : 0;
  int v1 = (base + 1 < N) ? cnt[base + 1] : 0;
  int v2 = (base + 2 < N) ? cnt[base + 2] : 0;
  int v3 = (base + 3 < N) ? cnt[base + 3] : 0;
  int tsum = v0 + v1 + v2 + v3;
  sh[tid] = tsum;
  __syncthreads();
  for (int off = 1; off < 256; off <<= 1) {
    int t2 = (tid >= off) ? sh[tid - off] : 0;
    __syncthreads();
    sh[tid] += t2;
    __syncthreads();
  }
  int incl = sh[tid];
  if (tid == 255) blocksums[blockIdx.x] = incl;
  int run = incl - tsum;
  if (base + 0 < N) excl[base + 0] = run; run += v0;
  if (base + 1 < N) excl[base + 1] = run; run += v1;
  if (base + 2 < N) excl[base + 2] = run; run += v2;
  if (base + 3 < N) excl[base + 3] = run;
}

__global__ void scan2(int* __restrict__ blocksums, int nb) {
  __shared__ int sh[256];
  int tid = threadIdx.x;
  int v = (tid < nb) ? blocksums[tid] : 0;
  sh[tid] = v;
  __syncthreads();
  for (int off = 1; off < 256; off <<= 1) {
    int t2 = (tid >= off) ? sh[tid - off] : 0;
    __syncthreads();
    sh[tid] += t2;
    __syncthreads();
  }
  if (tid < nb) blocksums[tid] = sh[tid] - v;
}

__global__ __launch_bounds__(256) void scan3(int* __restrict__ offs,
                                             const int* __restrict__ blocksums, int N,
                                             int Etot) {
  int t = blockIdx.x * 256 + threadIdx.x;
  if (t < N) offs[t] += blocksums[t >> 10];
  if (t == 0) offs[N] = Etot;
}

__global__ __launch_bounds__(256) void csr_fill2(
    const int* __restrict__ dst0, const int* __restrict__ src0, const int* __restrict__ et0,
    const int* __restrict__ dst1, const int* __restrict__ src1, const int* __restrict__ et1,
    const int* __restrict__ offs, const int* __restrict__ rank,
    int* __restrict__ elist) {
  int t = blockIdx.x * 256 + threadIdx.x;
  if (t < E0N) {
    int p = offs[dst0[t]] + rank[t];
    elist[p] = (src0[t] << 2) | et0[t];
  } else if (t < ET) {
    int t2 = t - E0N;
    int p = offs[NE0 + dst1[t2]] + rank[t];
    elist[p] = (src1[t2] << 2) | et1[t2];
  }
}

// ---------- fused flash attention + skip combine (R7) ------------------------
// R6 post-mortem: VALU 46% (=45us floor), rest latency. Two FIFO leaks fixed:
// (1) ve type-table loads were VMEM consumed same-iteration -> any waitcnt
//     covering them forces OLDER in-flight next-batch gathers to complete
//     (vmcnt counts FIFO: waiting for a newer load drains all older ones).
//     Fix: ve -> LDS (2KB, padded stride 136 so the 4 dst-slots' type rows
//     hit different bank groups). Table reads now lgkmcnt -- decoupled.
//     Only VMEM consumes left are loads issued >=1 iteration earlier ->
//     compiler can emit counted vmcnt(N), gathers stay in flight.
// (2) 256-thread blocks retired at the max of 4 independent waves (degree
//     imbalance) -> 64-thread blocks, wave-granular retire.
// 4 dsts/wave, 16 lanes/dst, 8 consecutive dims/lane; KV row = 16 x {K8|V8}.
__device__ __forceinline__ float sel4(float s0, float s1, float s2, float s3, int ty) {
  float a = (ty & 1) ? s1 : s0;
  float b = (ty & 1) ? s3 : s2;
  return (ty & 2) ? b : a;
}

__global__ __launch_bounds__(64) void attn_fused(
    const int* __restrict__ elist, const int* __restrict__ offs,
    const u16* __restrict__ Q, const u16* __restrict__ KV,
    const float* __restrict__ ke, const float* __restrict__ ve,
    const u16* __restrict__ skipb, float* __restrict__ outp, int N) {
  int wave = blockIdx.x;
  int lane = threadIdx.x;
  int which = lane >> 4;   // dst slot within wave
  int sub = lane & 15;     // 16 lanes per dst
  int d = wave * 4 + which;
  bool active = d < N;
  int dc = active ? d : 0;
  int dim0 = sub * 8;      // 8 consecutive dims per lane; head = sub>>1
  int sub16 = sub * 16;    // u16 offset of this lane's group within a KV row

  // stage ve into LDS: [4][136] floats (pad 8 -> per-type bank shift)
  __shared__ float vels[4 * 136];
  for (int i = lane; i < 512; i += 64) {
    int t = i >> 7, c = i & 127;
    vels[t * 136 + c] = ve[t * 128 + c];
  }
  __syncthreads();

  // Q: 8 dims as 4 packed bf16 pairs (already scaled by 1/sqrt(d))
  uint4 qp = *(const uint4*)(Q + (size_t)dc * D + dim0);
  f32x2 u0 = unpk(qp.x), u1 = unpk(qp.y), u2 = unpk(qp.z), u3 = unpk(qp.w);

  // per-type q . (We ek) : reduce over head (2 lanes)
  float qk0, qk1, qk2, qk3;
#pragma unroll
  for (int ty = 0; ty < 4; ++ty) {
    const float* kt = ke + ty * D + dim0;
    float4 ka = *(const float4*)kt;
    float4 kb = *(const float4*)(kt + 4);
    float p = u0.x * ka.x + u0.y * ka.y + u1.x * ka.z + u1.y * ka.w +
              u2.x * kb.x + u2.y * kb.y + u3.x * kb.z + u3.y * kb.w;
    p += __shfl_xor(p, 1, 64);
    if (ty == 0) qk0 = p; else if (ty == 1) qk1 = p; else if (ty == 2) qk2 = p; else qk3 = p;
  }

  int j0 = active ? offs[d] : 0;
  int j1 = active ? offs[d + 1] : 0;
  int j = j0;

  // --- pipeline prologue: codes for j and j+4 ---
  int cp0, cp1, cp2, cp3;      // current
  int fp0, fp1, fp2, fp3;      // future (j+4)
  {
    int i0 = (j + 0 < j1) ? j + 0 : 0;
    int i1 = (j + 1 < j1) ? j + 1 : 0;
    int i2 = (j + 2 < j1) ? j + 2 : 0;
    int i3 = (j + 3 < j1) ? j + 3 : 0;
    cp0 = elist[i0]; cp1 = elist[i1]; cp2 = elist[i2]; cp3 = elist[i3];
    int k0 = (j + 4 < j1) ? j + 4 : 0;
    int k1 = (j + 5 < j1) ? j + 5 : 0;
    int k2 = (j + 6 < j1) ? j + 6 : 0;
    int k3 = (j + 7 < j1) ? j + 7 : 0;
    fp0 = elist[k0]; fp1 = elist[k1]; fp2 = elist[k2]; fp3 = elist[k3];
  }
  // K+V for current batch (one-time exposed latency)
  uint4 ck0 = *(const uint4*)(KV + (size_t)(cp0 >> 2) * 256 + sub16);
  uint4 ck1 = *(const uint4*)(KV + (size_t)(cp1 >> 2) * 256 + sub16);
  uint4 ck2 = *(const uint4*)(KV + (size_t)(cp2 >> 2) * 256 + sub16);
  uint4 ck3 = *(const uint4*)(KV + (size_t)(cp3 >> 2) * 256 + sub16);
  uint4 cw0 = *(const uint4*)(KV + (size_t)(cp0 >> 2) * 256 + sub16 + 8);
  uint4 cw1 = *(const uint4*)(KV + (size_t)(cp1 >> 2) * 256 + sub16 + 8);
  uint4 cw2 = *(const uint4*)(KV + (size_t)(cp2 >> 2) * 256 + sub16 + 8);
  uint4 cw3 = *(const uint4*)(KV + (size_t)(cp3 >> 2) * 256 + sub16 + 8);

  float m = -INFINITY, s = 0.f;
  f32x2 acc01 = {0.f, 0.f}, acc23 = {0.f, 0.f}, acc45 = {0.f, 0.f}, acc67 = {0.f, 0.f};

  while (__any(j < j1)) {
    int jn = j + 4;
    // issue K+V for NEXT batch (codes fp* already resident -> no chain)
    uint4 nk0 = *(const uint4*)(KV + (size_t)(fp0 >> 2) * 256 + sub16);
    uint4 nk1 = *(const uint4*)(KV + (size_t)(fp1 >> 2) * 256 + sub16);
    uint4 nk2 = *(const uint4*)(KV + (size_t)(fp2 >> 2) * 256 + sub16);
    uint4 nk3 = *(const uint4*)(KV + (size_t)(fp3 >> 2) * 256 + sub16);
    uint4 nw0 = *(const uint4*)(KV + (size_t)(fp0 >> 2) * 256 + sub16 + 8);
    uint4 nw1 = *(const uint4*)(KV + (size_t)(fp1 >> 2) * 256 + sub16 + 8);
    uint4 nw2 = *(const uint4*)(KV + (size_t)(fp2 >> 2) * 256 + sub16 + 8);
    uint4 nw3 = *(const uint4*)(KV + (size_t)(fp3 >> 2) * 256 + sub16 + 8);
    // load codes for batch j+8 (consumed next iteration)
    int g0 = (jn + 4 < j1) ? jn + 4 : 0;
    int g1 = (jn + 5 < j1) ? jn + 5 : 0;
    int g2 = (jn + 6 < j1) ? jn + 6 : 0;
    int g3 = (jn + 7 < j1) ? jn + 7 : 0;
    int gp0 = elist[g0], gp1 = elist[g1], gp2 = elist[g2], gp3 = elist[g3];

    int n = j1 - j;
    if (n > 0) {
      int t0 = cp0 & 3, t1 = cp1 & 3, t2 = cp2 & 3, t3 = cp3 & 3;
      // type-value rows from LDS (lgkmcnt -- does not touch the gather FIFO)
      const float* vp0 = vels + t0 * 136 + dim0;
      const float* vp1 = vels + t1 * 136 + dim0;
      const float* vp2 = vels + t2 * 136 + dim0;
      const float* vp3 = vels + t3 * 136 + dim0;
      float4 va0 = *(const float4*)vp0, vb0 = *(const float4*)(vp0 + 4);
      float4 va1 = *(const float4*)vp1, vb1 = *(const float4*)(vp1 + 4);
      float4 va2 = *(const float4*)vp2, vb2 = *(const float4*)(vp2 + 4);
      float4 va3 = *(const float4*)vp3, vb3 = *(const float4*)(vp3 + 4);

      // q . k over lane's 8 dims (bf16 dot2), then head-reduce over 2 lanes
      float p0 = dot2bf(qp.x, ck0.x, dot2bf(qp.y, ck0.y, dot2bf(qp.z, ck0.z, dot2bf(qp.w, ck0.w, 0.f))));
      float p1 = dot2bf(qp.x, ck1.x, dot2bf(qp.y, ck1.y, dot2bf(qp.z, ck1.z, dot2bf(qp.w, ck1.w, 0.f))));
      float p2 = dot2bf(qp.x, ck2.x, dot2bf(qp.y, ck2.y, dot2bf(qp.z, ck2.z, dot2bf(qp.w, ck2.w, 0.f))));
      float p3 = dot2bf(qp.x, ck3.x, dot2bf(qp.y, ck3.y, dot2bf(qp.z, ck3.z, dot2bf(qp.w, ck3.w, 0.f))));
      p0 += __shfl_xor(p0, 1, 64);
      p1 += __shfl_xor(p1, 1, 64);
      p2 += __shfl_xor(p2, 1, 64);
      p3 += __shfl_xor(p3, 1, 64);

      float l0 = p0 + sel4(qk0, qk1, qk2, qk3, t0);
      float l1 = p1 + sel4(qk0, qk1, qk2, qk3, t1);
      float l2 = p2 + sel4(qk0, qk1, qk2, qk3, t2);
      float l3 = p3 + sel4(qk0, qk1, qk2, qk3, t3);
      l0 = l0 >= 0.f ? l0 : 0.2f * l0;
      l1 = l1 >= 0.f ? l1 : 0.2f * l1;
      l2 = l2 >= 0.f ? l2 : 0.2f * l2;
      l3 = l3 >= 0.f ? l3 : 0.2f * l3;
      if (n < 2) l1 = -INFINITY;
      if (n < 3) l2 = -INFINITY;
      if (n < 4) l3 = -INFINITY;
      float mb = fmaxf(fmaxf(l0, l1), fmaxf(l2, l3));
      float mn = fmaxf(m, mb);
      float f = __expf(m - mn);
      float a0 = __expf(l0 - mn);
      float a1 = __expf(l1 - mn);
      float a2 = __expf(l2 - mn);
      float a3 = __expf(l3 - mn);
      s = s * f + ((a0 + a1) + (a2 + a3));
      f32x2 ff = {f, f};
      acc01 *= ff; acc23 *= ff; acc45 *= ff; acc67 *= ff;
      f32x2 aa0 = {a0, a0}, aa1 = {a1, a1}, aa2 = {a2, a2}, aa3 = {a3, a3};
      acc01 = fma2(aa0, unpk(cw0.x) + (f32x2){va0.x, va0.y}, acc01);
      acc23 = fma2(aa0, unpk(cw0.y) + (f32x2){va0.z, va0.w}, acc23);
      acc45 = fma2(aa0, unpk(cw0.z) + (f32x2){vb0.x, vb0.y}, acc45);
      acc67 = fma2(aa0, unpk(cw0.w) + (f32x2){vb0.z, vb0.w}, acc67);
      acc01 = fma2(aa1, unpk(cw1.x) + (f32x2){va1.x, va1.y}, acc01);
      acc23 = fma2(aa1, unpk(cw1.y) + (f32x2){va1.z, va1.w}, acc23);
      acc45 = fma2(aa1, unpk(cw1.z) + (f32x2){vb1.x, vb1.y}, acc45);
      acc67 = fma2(aa1, unpk(cw1.w) + (f32x2){vb1.z, vb1.w}, acc67);
      acc01 = fma2(aa2, unpk(cw2.x) + (f32x2){va2.x, va2.y}, acc01);
      acc23 = fma2(aa2, unpk(cw2.y) + (f32x2){va2.z, va2.w}, acc23);
      acc45 = fma2(aa2, unpk(cw2.z) + (f32x2){vb2.x, vb2.y}, acc45);
      acc67 = fma2(aa2, unpk(cw2.w) + (f32x2){vb2.z, vb2.w}, acc67);
      acc01 = fma2(aa3, unpk(cw3.x) + (f32x2){va3.x, va3.y}, acc01);
      acc23 = fma2(aa3, unpk(cw3.y) + (f32x2){va3.z, va3.w}, acc23);
      acc45 = fma2(aa3, unpk(cw3.z) + (f32x2){vb3.x, vb3.y}, acc45);
      acc67 = fma2(aa3, unpk(cw3.w) + (f32x2){vb3.z, vb3.w}, acc67);
      m = mn;
    }
    // rotate pipeline
    cp0 = fp0; cp1 = fp1; cp2 = fp2; cp3 = fp3;
    fp0 = gp0; fp1 = gp1; fp2 = gp2; fp3 = gp3;
    ck0 = nk0; ck1 = nk1; ck2 = nk2; ck3 = nk3;
    cw0 = nw0; cw1 = nw1; cw2 = nw2; cw3 = nw3;
    j = jn;
  }
  if (active) {
    float inv = 1.f / (s + 1e-16f);
    float hf = 0.5f * inv;
    uint4 sk = *(const uint4*)(skipb + (size_t)d * D + dim0);
    f32x2 s0 = unpk(sk.x), s1 = unpk(sk.y), s2 = unpk(sk.z), s3 = unpk(sk.w);
    float* op = outp + (size_t)d * D + dim0;
    float4 o0, o1;
    o0.x = 0.5f * s0.x + hf * acc01.x;
    o0.y = 0.5f * s0.y + hf * acc01.y;
    o0.z = 0.5f * s1.x + hf * acc23.x;
    o0.w = 0.5f * s1.y + hf * acc23.y;
    o1.x = 0.5f * s2.x + hf * acc45.x;
    o1.y = 0.5f * s2.y + hf * acc45.y;
    o1.z = 0.5f * s3.x + hf * acc67.x;
    o1.w = 0.5f * s3.y + hf * acc67.y;
    *(float4*)op = o0;
    *(float4*)(op + 4) = o1;
  }
}

// ---------- batch norm ----------
__global__ __launch_bounds__(256) void bn_reduce(const float* __restrict__ h,
                                                 float* __restrict__ sums, int N) {
  int c = threadIdx.x & 127;
  int rofs = threadIdx.x >> 7;
  float s0 = 0.f, s1 = 0.f;
  for (int r = blockIdx.x * 2 + rofs; r < N; r += gridDim.x * 2) {
    float v = h[(size_t)r * 128 + c];
    s0 += v;
    s1 += v * v;
  }
  __shared__ float ls[256], lq[256];
  ls[threadIdx.x] = s0;
  lq[threadIdx.x] = s1;
  __syncthreads();
  if (threadIdx.x < 128) {
    atomicAdd(&sums[c], ls[threadIdx.x] + ls[threadIdx.x + 128]);
    atomicAdd(&sums[128 + c], lq[threadIdx.x] + lq[threadIdx.x + 128]);
  }
}

__global__ __launch_bounds__(256) void bn_apply(const float* __restrict__ h,
                                                u16* __restrict__ hbf,
                                                const float* __restrict__ sums,
                                                const float* __restrict__ gamma,
                                                const float* __restrict__ beta,
                                                float invN, int total) {
  __shared__ float sc[128], sh[128];
  int tid = threadIdx.x;
  if (tid < 128) {
    float mu = sums[tid] * invN;
    float var = sums[128 + tid] * invN - mu * mu;
    float inv = rsqrtf(var + 1e-5f);
    float s = gamma[tid] * inv;
    sc[tid] = s;
    sh[tid] = beta[tid] - mu * s;
  }
  __syncthreads();
  int i = blockIdx.x * 256 + tid;
  if (i < total) {
    int c = i & 127;
    hbf[i] = f2bf(h[i] * sc[c] + sh[c]);
  }
}

// ---------- launch ----------
extern "C" void kernel_launch(void* const* d_in, const int* in_sizes, int n_in,
                              void* d_out, int out_size, void* d_ws, size_t ws_size,
                              hipStream_t stream) {
  const float* x        = (const float*)d_in[0];
  const int*   ei0      = (const int*)d_in[1];
  const int*   et0      = (const int*)d_in[2];
  const int*   ei1      = (const int*)d_in[3];
  const int*   et1      = (const int*)d_in[4];
  const float* emb_type = (const float*)d_in[5];
  const float* emb_attr = (const float*)d_in[6];
  const float* v2e_Wq   = (const float*)d_in[7];
  const float* v2e_Wk   = (const float*)d_in[8];
  const float* v2e_Wv   = (const float*)d_in[9];
  const float* v2e_We   = (const float*)d_in[10];
  const float* v2e_Wsk  = (const float*)d_in[11];
  const float* e2_Wq    = (const float*)d_in[12];
  const float* e2_Wk    = (const float*)d_in[13];
  const float* e2_Wv    = (const float*)d_in[14];
  const float* e2_We    = (const float*)d_in[15];
  const float* e2_Wsk   = (const float*)d_in[16];
  const float* bn_gamma = (const float*)d_in[17];
  const float* bn_beta  = (const float*)d_in[18];
  float* out = (float*)d_out;

  // workspace layout
  char* wsb = (char*)d_ws;
  size_t off = 0;
  u16* xb  = (u16*)(wsb + off);  off += (size_t)NSRC * D * 2;
  u16* KVb = (u16*)(wsb + off);  off += (size_t)NSRC * D * 2 * 2;  // interleaved K|V
  u16* Qb  = (u16*)(wsb + off);  off += (size_t)NE0 * D * 2;
  u16* Sb  = (u16*)(wsb + off);  off += (size_t)NE0 * D * 2;
  float* hb = (float*)(wsb + off); off += (size_t)NE0 * D * 4;
  u16* hbf = (u16*)(wsb + off);  off += (size_t)NE0 * D * 2;
  u16* wtAll = (u16*)(wsb + off); off += 8 * 16384 * 2;
  int* elist = (int*)(wsb + off);  off += (size_t)ET * 4;
  int* rank  = (int*)(wsb + off);  off += (size_t)ET * 4;
  int* offs  = (int*)(wsb + off);  off += ((size_t)NT + 8) * 4;
  int* bsums = (int*)(wsb + off);  off += 1024;
  float* kv  = (float*)(wsb + off); off += 4 * 512 * 4;
  float* bnsums = (float*)(wsb + off); off += 256 * 4;  // sum[128] | sumsq[128]

  u16* wtK0 = wtAll + 0 * 16384;
  u16* wtV0 = wtAll + 1 * 16384;
  u16* wtQ0 = wtAll + 2 * 16384;
  u16* wtS0 = wtAll + 3 * 16384;
  u16* wtK1 = wtAll + 4 * 16384;
  u16* wtV1 = wtAll + 5 * 16384;
  u16* wtQ1 = wtAll + 6 * 16384;
  u16* wtS1 = wtAll + 7 * 16384;
  float* kep0 = kv;
  float* vep0 = kv + 512;
  float* kep1 = kv + 1024;
  float* vep1 = kv + 1536;

  const int* src0 = ei0;
  const int* dst0 = ei0 + E0N;
  const int* src1 = ei1;
  const int* dst1 = ei1 + E1N;

  // 1: mega-prep (cast + weights + embs + zeroing)
  prep_all<<<BC + 64 + 4 + BZ + 1, 256, 0, stream>>>(
      x, xb, v2e_Wk, v2e_Wv, v2e_Wq, v2e_Wsk, e2_Wk, e2_Wv, e2_Wq, e2_Wsk,
      wtAll, emb_type, emb_attr, v2e_We, e2_We, kv, offs, bnsums);

  // 2-6: CSR for both layers
  csr_count2<<<(ET + 255) / 256, 256, 0, stream>>>(dst0, dst1, offs, rank);
  {
    int nb = (NT + 1023) / 1024;
    scan1<<<nb, 256, 0, stream>>>(offs, offs, bsums, NT);
    scan2<<<1, 256, 0, stream>>>(bsums, nb);
    scan3<<<(NT + 255) / 256, 256, 0, stream>>>(offs, bsums, NT, ET);
  }
  csr_fill2<<<(ET + 255) / 256, 256, 0, stream>>>(dst0, src0, et0, dst1, src1, et1,
                                                  offs, rank, elist);

  // 7-10: layer 0
  {
    int nKV = (NSRC + 127) / 128, nQS = (NE0 + 127) / 128;
    gemm_quad<<<nKV + nQS, 512, 0, stream>>>(xb, wtK0, wtV0, KVb, NSRC, nKV,
                                             wtQ0, wtS0, Qb, Sb, NE0);
  }
  attn_fused<<<(NE0 + 3) / 4, 64, 0, stream>>>(elist, offs, Qb, KVb, kep0, vep0,
                                               Sb, hb, NE0);
  bn_reduce<<<256, 256, 0, stream>>>(hb, bnsums, NE0);
  bn_apply<<<(NE0 * D + 255) / 256, 256, 0, stream>>>(hb, hbf, bnsums, bn_gamma, bn_beta,
                                                      1.0f / (float)NE0, NE0 * D);

  // 11-12: layer 1
  {
    int nKV = (NE0 + 127) / 128, nQS = (NE1 + 127) / 128;
    gemm_quad<<<nKV + nQS, 512, 0, stream>>>(hbf, wtK1, wtV1, KVb, NE0, nKV,
                                             wtQ1, wtS1, Qb, Sb, NE1);
  }
  attn_fused<<<(NE1 + 3) / 4, 64, 0, stream>>>(elist, offs + NE0, Qb, KVb, kep1, vep1,
                                               Sb, out, NE1);
}